// Round 1
// baseline (1033.854 us; speedup 1.0000x reference)
//
#include <hip/hip_runtime.h>
#include <math.h>

#define B_ 256
#define N_ 128
#define D_ 128
#define L_ 32
#define E_ 262144
#define P_ 8128
#define PW_ 254          // bitmap words per graph = 8128/32

// workspace layout in float units
#define AGG_OFF 0               // 32768*128 = 4194304 floats
#define KLS_OFF 4194304         // 256 floats
#define BM_OFF  4194560         // 65024 u32
#define RES_OFF 4259584         // 256 floats
#define Z_OFF   4259840         // 32768*32 = 1048576 floats
#define ZERO_BYTES (4259584ull * 4ull)   // zero agg + kls + bitmap

// ---------------------------------------------------------------------------
// Edge scatter: agg[dst] += x[src]; agg[src] += x[dst]; set target bitmap bit.
// 32 threads per edge, each handles 4 floats of both directions.
__global__ __launch_bounds__(256) void k_scatter(
    const int* __restrict__ ei, const float* __restrict__ x,
    float* __restrict__ agg, unsigned* __restrict__ bitmap)
{
    int gid = blockIdx.x * 256 + threadIdx.x;
    int e = gid >> 5;
    int q = gid & 31;
    int src = ei[e];
    int dst = ei[E_ + e];
    int d0 = q << 2;
    float4 xs = *(const float4*)(x + (size_t)src * D_ + d0);
    float4 xd = *(const float4*)(x + (size_t)dst * D_ + d0);
    float* as = agg + (size_t)src * D_ + d0;
    float* ad = agg + (size_t)dst * D_ + d0;
    atomicAdd(ad + 0, xs.x); atomicAdd(ad + 1, xs.y);
    atomicAdd(ad + 2, xs.z); atomicAdd(ad + 3, xs.w);
    atomicAdd(as + 0, xd.x); atomicAdd(as + 1, xd.y);
    atomicAdd(as + 2, xd.z); atomicAdd(as + 3, xd.w);
    if (q == 0) {
        int li = src & (N_ - 1);
        int lj = dst & (N_ - 1);
        int g  = src >> 7;
        int p  = li * (2 * N_ - li - 1) / 2 + (lj - li - 1);
        atomicOr(bitmap + g * PW_ + (p >> 5), 1u << (p & 31));
    }
}

// ---------------------------------------------------------------------------
// Fused encoder: per 32-row tile, h = relu((x+agg)@W1 + b1) (W1 in LDS),
// then mu/ls = h@[Wmu|Wls]+bias, z = mu + exp(ls)*eps, KL accumulation.
// LDS: main phase W1s[128][128] (16384 f) + XA[32][128] (4096 f).
// Epilogue reuses the W1s region: HS[32][132] + WB[128][64] + BV[64] + RED[256].
__global__ __launch_bounds__(256) void k_encoder(
    const float* __restrict__ x, const float* __restrict__ agg,
    const float* __restrict__ W1, const float* __restrict__ b1,
    const float* __restrict__ Wmu, const float* __restrict__ bmu,
    const float* __restrict__ Wls, const float* __restrict__ bls,
    const float* __restrict__ eps,
    float* __restrict__ z, float* __restrict__ kls)
{
    __shared__ float sm[20480];       // 80 KiB -> 2 blocks/CU
    float* W1s = sm;                  // [0,16384)
    float* XA  = sm + 16384;          // [16384, 20480)  xa[r][d], 32x128
    float* HS  = sm;                  // epilogue: [0, 4224)     hs[r][132]
    float* WB  = sm + 4224;           // epilogue: [4224, 12416) wb[d][64]
    float* BV  = sm + 12416;          // epilogue: [12416,12480)
    float* RED = sm + 12480;          // epilogue: [12480,12736)

    int t = threadIdx.x;
    int row0 = blockIdx.x * 32;

    // ---- stage XA = x + agg (32x128), W1 (128x128) ----
    #pragma unroll
    for (int i = 0; i < 4; ++i) {
        int c = t + i * 256;          // 1024 float4 chunks
        int r = c >> 5, d4 = (c & 31) << 2;
        float4 xv = *(const float4*)(x   + (size_t)(row0 + r) * D_ + d4);
        float4 av = *(const float4*)(agg + (size_t)(row0 + r) * D_ + d4);
        float4 s; s.x = xv.x + av.x; s.y = xv.y + av.y; s.z = xv.z + av.z; s.w = xv.w + av.w;
        *(float4*)(XA + r * D_ + d4) = s;
    }
    #pragma unroll
    for (int i = 0; i < 16; ++i) {
        int c = t + i * 256;          // 4096 float4 chunks
        ((float4*)W1s)[c] = ((const float4*)W1)[c];
    }
    __syncthreads();

    // ---- main GEMM: 4x4 micro-tile per thread ----
    int r0 = (t >> 5) << 2;           // rows {0,4,...,28}
    int c0 = (t & 31) << 2;           // cols {0,4,...,124}
    float acc[4][4];
    #pragma unroll
    for (int a = 0; a < 4; ++a)
        #pragma unroll
        for (int b = 0; b < 4; ++b) acc[a][b] = 0.0f;

    for (int d = 0; d < 128; d += 4) {
        float4 av[4], wv[4];
        #pragma unroll
        for (int ri = 0; ri < 4; ++ri) av[ri] = *(const float4*)(XA + (r0 + ri) * D_ + d);
        #pragma unroll
        for (int dk = 0; dk < 4; ++dk) wv[dk] = *(const float4*)(W1s + (d + dk) * D_ + c0);
        #pragma unroll
        for (int ri = 0; ri < 4; ++ri) {
            acc[ri][0] += av[ri].x * wv[0].x + av[ri].y * wv[1].x + av[ri].z * wv[2].x + av[ri].w * wv[3].x;
            acc[ri][1] += av[ri].x * wv[0].y + av[ri].y * wv[1].y + av[ri].z * wv[2].y + av[ri].w * wv[3].y;
            acc[ri][2] += av[ri].x * wv[0].z + av[ri].y * wv[1].z + av[ri].z * wv[2].z + av[ri].w * wv[3].z;
            acc[ri][3] += av[ri].x * wv[0].w + av[ri].y * wv[1].w + av[ri].z * wv[2].w + av[ri].w * wv[3].w;
        }
    }
    __syncthreads();   // done reading W1s/XA; safe to overwrite with epilogue data

    // ---- bias + relu, store h tile; stage Wmu/Wls/biases ----
    float4 bb = *(const float4*)(b1 + c0);
    #pragma unroll
    for (int ri = 0; ri < 4; ++ri) {
        float4 h;
        h.x = fmaxf(acc[ri][0] + bb.x, 0.0f);
        h.y = fmaxf(acc[ri][1] + bb.y, 0.0f);
        h.z = fmaxf(acc[ri][2] + bb.z, 0.0f);
        h.w = fmaxf(acc[ri][3] + bb.w, 0.0f);
        *(float4*)(HS + (r0 + ri) * 132 + c0) = h;
    }
    #pragma unroll
    for (int i = 0; i < 16; ++i) {
        int c = t + i * 256;          // 4096 entries
        int d = c >> 5, l = c & 31;
        WB[d * 64 + l]      = Wmu[c];
        WB[d * 64 + 32 + l] = Wls[c];
    }
    if (t < 32) { BV[t] = bmu[t]; BV[32 + t] = bls[t]; }
    __syncthreads();

    // ---- mu/ls: thread -> (row r, latents l0..l0+3, both mu and ls) ----
    int r  = t >> 3;
    int l0 = (t & 7) << 2;
    float4 mu; mu.x = mu.y = mu.z = mu.w = 0.0f;
    float4 ls; ls.x = ls.y = ls.z = ls.w = 0.0f;
    for (int d = 0; d < 128; d += 4) {
        float4 hv = *(const float4*)(HS + r * 132 + d);
        float hk[4] = {hv.x, hv.y, hv.z, hv.w};
        #pragma unroll
        for (int k = 0; k < 4; ++k) {
            float4 wm = *(const float4*)(WB + (d + k) * 64 + l0);
            float4 wl = *(const float4*)(WB + (d + k) * 64 + 32 + l0);
            mu.x += hk[k] * wm.x; mu.y += hk[k] * wm.y; mu.z += hk[k] * wm.z; mu.w += hk[k] * wm.w;
            ls.x += hk[k] * wl.x; ls.y += hk[k] * wl.y; ls.z += hk[k] * wl.z; ls.w += hk[k] * wl.w;
        }
    }
    float4 bm = *(const float4*)(BV + l0);
    float4 bl = *(const float4*)(BV + 32 + l0);
    mu.x += bm.x; mu.y += bm.y; mu.z += bm.z; mu.w += bm.w;
    ls.x += bl.x; ls.y += bl.y; ls.z += bl.z; ls.w += bl.w;

    float4 sd; sd.x = expf(ls.x); sd.y = expf(ls.y); sd.z = expf(ls.z); sd.w = expf(ls.w);
    float4 ev = *(const float4*)(eps + (size_t)(row0 + r) * L_ + l0);
    float4 zv;
    zv.x = mu.x + sd.x * ev.x; zv.y = mu.y + sd.y * ev.y;
    zv.z = mu.z + sd.z * ev.z; zv.w = mu.w + sd.w * ev.w;
    *(float4*)(z + (size_t)(row0 + r) * L_ + l0) = zv;

    float kl =
        (sd.x * sd.x + mu.x * mu.x - 1.0f - 2.0f * ls.x) +
        (sd.y * sd.y + mu.y * mu.y - 1.0f - 2.0f * ls.y) +
        (sd.z * sd.z + mu.z * mu.z - 1.0f - 2.0f * ls.z) +
        (sd.w * sd.w + mu.w * mu.w - 1.0f - 2.0f * ls.w);
    RED[t] = kl;
    __syncthreads();
    for (int s = 128; s > 0; s >>= 1) {
        if (t < s) RED[t] += RED[t + s];
        __syncthreads();
    }
    if (t == 0) atomicAdd(kls + (row0 >> 7), 0.5f * RED[0]);
}

// ---------------------------------------------------------------------------
// Decoder: one block per graph. Full 128x128 Gram via 8x8 register tiles,
// softplus + bitmap-target on upper triangle, block-reduce -> res[b].
__global__ __launch_bounds__(256) void k_decoder(
    const float* __restrict__ z, const unsigned* __restrict__ bitmap,
    const float* __restrict__ kls, float* __restrict__ res)
{
    __shared__ float zT[32 * 132];    // zT[l][n], padded
    __shared__ unsigned bm[PW_];
    __shared__ float RED[256];
    int b = blockIdx.x, t = threadIdx.x;

    #pragma unroll
    for (int i = 0; i < 16; ++i) {
        int c = t + i * 256;          // 4096 elements
        int n = c >> 5, l = c & 31;
        zT[l * 132 + n] = z[((size_t)b * N_ + n) * L_ + l];
    }
    if (t < PW_) bm[t] = bitmap[b * PW_ + t];
    __syncthreads();

    int i0 = (t >> 4) << 3;           // 0..120
    int j0 = (t & 15) << 3;
    float g[8][8];
    #pragma unroll
    for (int a = 0; a < 8; ++a)
        #pragma unroll
        for (int c = 0; c < 8; ++c) g[a][c] = 0.0f;

    for (int l = 0; l < 32; ++l) {
        float4 a0 = *(const float4*)(zT + l * 132 + i0);
        float4 a1 = *(const float4*)(zT + l * 132 + i0 + 4);
        float4 b0 = *(const float4*)(zT + l * 132 + j0);
        float4 b1v = *(const float4*)(zT + l * 132 + j0 + 4);
        float za[8] = {a0.x, a0.y, a0.z, a0.w, a1.x, a1.y, a1.z, a1.w};
        float zb[8] = {b0.x, b0.y, b0.z, b0.w, b1v.x, b1v.y, b1v.z, b1v.w};
        #pragma unroll
        for (int a = 0; a < 8; ++a)
            #pragma unroll
            for (int c = 0; c < 8; ++c) g[a][c] += za[a] * zb[c];
    }

    float sum = 0.0f;
    #pragma unroll
    for (int a = 0; a < 8; ++a) {
        int i = i0 + a;
        #pragma unroll
        for (int c = 0; c < 8; ++c) {
            int j = j0 + c;
            if (j > i) {
                float lg = g[a][c];
                int p = i * (2 * N_ - i - 1) / 2 + (j - i - 1);
                unsigned bit = (bm[p >> 5] >> (p & 31)) & 1u;
                float sp = log1pf(expf(-fabsf(lg))) + fmaxf(lg, 0.0f);
                sum += bit ? (lg - sp) : (-sp);
            }
        }
    }
    RED[t] = sum;
    __syncthreads();
    for (int s = 128; s > 0; s >>= 1) {
        if (t < s) RED[t] += RED[t + s];
        __syncthreads();
    }
    if (t == 0) res[b] = kls[b] - RED[0];   // per-graph (kls - log_probs)
}

// ---------------------------------------------------------------------------
__global__ __launch_bounds__(256) void k_finalize(
    const float* __restrict__ res, float* __restrict__ out)
{
    __shared__ float RED[256];
    int t = threadIdx.x;
    RED[t] = res[t];
    __syncthreads();
    for (int s = 128; s > 0; s >>= 1) {
        if (t < s) RED[t] += RED[t + s];
        __syncthreads();
    }
    if (t == 0) out[0] = RED[0] * (1.0f / 256.0f);
}

// ---------------------------------------------------------------------------
extern "C" void kernel_launch(void* const* d_in, const int* in_sizes, int n_in,
                              void* d_out, int out_size, void* d_ws, size_t ws_size,
                              hipStream_t stream) {
    const float* x   = (const float*)d_in[0];
    const int*   ei  = (const int*)d_in[1];
    // d_in[2] = batch (unused; block-contiguous layout is known)
    const float* eps = (const float*)d_in[3];
    const float* W1  = (const float*)d_in[4];
    const float* b1  = (const float*)d_in[5];
    const float* Wmu = (const float*)d_in[6];
    const float* bmu = (const float*)d_in[7];
    const float* Wls = (const float*)d_in[8];
    const float* bls = (const float*)d_in[9];

    float* ws = (float*)d_ws;
    float*    agg    = ws + AGG_OFF;
    float*    kls    = ws + KLS_OFF;
    unsigned* bitmap = (unsigned*)(ws + BM_OFF);
    float*    res    = ws + RES_OFF;
    float*    z      = ws + Z_OFF;

    hipMemsetAsync(d_ws, 0, ZERO_BYTES, stream);  // agg + kls + bitmap

    k_scatter <<<E_ * 32 / 256, 256, 0, stream>>>(ei, x, agg, bitmap);
    k_encoder <<<(B_ * N_) / 32, 256, 0, stream>>>(x, agg, W1, b1, Wmu, bmu,
                                                   Wls, bls, eps, z, kls);
    k_decoder <<<B_, 256, 0, stream>>>(z, bitmap, kls, res);
    k_finalize<<<1, 256, 0, stream>>>(res, (float*)d_out);
}

// Round 2
// 266.915 us; speedup vs baseline: 3.8733x; 3.8733x over previous
//
#include <hip/hip_runtime.h>
#include <math.h>

#define B_ 256
#define N_ 128
#define D_ 128
#define L_ 32
#define E_ 262144
#define PW_ 254          // bitmap words per graph = 8128/32
#define CAP 2048         // per-graph edge capacity (mean 1024, sigma 32)

// workspace layout (32-bit units):
// cnt  [0, 256)             u32 per-graph edge counts (memset to 0)
// ebuf [256, 256+B*CAP)     u32 packed (li | lj<<16)
// res  [256+B*CAP, +256)    f32 per-graph (kls - log_probs)
#define EBUF_OFF 256
#define RES_OFF  (256 + B_ * CAP)

// ---------------------------------------------------------------------------
// Bucket edges by graph. One thread per edge.
__global__ __launch_bounds__(256) void k_bucket(
    const int* __restrict__ ei, unsigned* __restrict__ cnt,
    unsigned* __restrict__ ebuf)
{
    int e = blockIdx.x * 256 + threadIdx.x;
    int src = ei[e], dst = ei[E_ + e];
    int g = src >> 7;
    unsigned slot = atomicAdd(&cnt[g], 1u);
    if (slot < CAP)
        ebuf[(g << 11) + slot] = (unsigned)(src & 127) | ((unsigned)(dst & 127) << 16);
}

// ---------------------------------------------------------------------------
// Fully-fused per-graph VAE: one block per graph.
// LDS regions (floats, strides chosen for 16B alignment + <=2-way conflicts):
//   RA[16896]: adjacency Ã (I+A, stride 132) -> W1 [k][c] (132) -> HT [c][n] (132) -> ZT [l][n] (132)
//   RX[16896]: X [n][d] (132) -> XAT [d][n] (132) -> WB [k][64] (64) @0 + MLS [n][68] @8192
// GEMM register tiling: thread (ty=t>>4, tx=t&15) owns quadrant rows
// {4ty+i, 64+4ty+i} x cols {4tx+j, 64+4tx+j} -> all LDS reads are <=2 addr/bank.
__global__ __launch_bounds__(256) void k_graph(
    const float* __restrict__ x, const float* __restrict__ eps,
    const float* __restrict__ W1, const float* __restrict__ b1,
    const float* __restrict__ Wmu, const float* __restrict__ bmu,
    const float* __restrict__ Wls, const float* __restrict__ bls,
    const unsigned* __restrict__ cnt, const unsigned* __restrict__ ebuf,
    float* __restrict__ res)
{
    __shared__ float RA[16896];
    __shared__ float RX[16896];
    __shared__ unsigned BM[PW_];
    __shared__ float RED[256];
    __shared__ float sKL;

    const int t = threadIdx.x;
    const int b = blockIdx.x;
    const int ty = t >> 4, tx = t & 15;
    const int gbase = b << 7;

    // ---- phase 0a: zero Ã + bitmap; stage X[n][d] (stride 132) ----
    for (int c = t; c < 4224; c += 256) ((float4*)RA)[c] = make_float4(0.f, 0.f, 0.f, 0.f);
    if (t < PW_) BM[t] = 0u;
    #pragma unroll
    for (int i = 0; i < 16; ++i) {
        int c = t + i * 256;              // 4096 float4 chunks
        int n = c >> 5, d4 = (c & 31) << 2;
        *(float4*)(RX + n * 132 + d4) = *(const float4*)(x + (size_t)(gbase + n) * D_ + d4);
    }
    __syncthreads();

    // ---- phase 0b: Ã = I + adjacency counts; target bitmap ----
    if (t < 128) RA[t * 132 + t] = 1.0f;
    int ec = (int)cnt[b];
    if (ec > CAP) ec = CAP;
    for (int e = t; e < ec; e += 256) {
        unsigned u = ebuf[(b << 11) + e];
        int li = (int)(u & 0xffffu), lj = (int)(u >> 16);
        atomicAdd(&RA[li * 132 + lj], 1.0f);
        atomicAdd(&RA[lj * 132 + li], 1.0f);
        int p = li * (255 - li) / 2 + (lj - li - 1);
        atomicOr(&BM[p >> 5], 1u << (p & 31));
    }
    __syncthreads();

    // ---- phase 1: XA = Ã @ X   (Ã symmetric -> read rows as columns) ----
    float acc[2][2][4][4];
    #pragma unroll
    for (int ri = 0; ri < 2; ++ri)
        #pragma unroll
        for (int ci = 0; ci < 2; ++ci)
            #pragma unroll
            for (int i = 0; i < 4; ++i)
                #pragma unroll
                for (int j = 0; j < 4; ++j) acc[ri][ci][i][j] = 0.f;

    #pragma unroll 4
    for (int k = 0; k < 128; ++k) {
        float4 a0 = *(const float4*)(RA + k * 132 + 4 * ty);
        float4 a1 = *(const float4*)(RA + k * 132 + 64 + 4 * ty);
        float4 w0 = *(const float4*)(RX + k * 132 + 4 * tx);
        float4 w1 = *(const float4*)(RX + k * 132 + 64 + 4 * tx);
        float av[2][4] = {{a0.x, a0.y, a0.z, a0.w}, {a1.x, a1.y, a1.z, a1.w}};
        float wv[2][4] = {{w0.x, w0.y, w0.z, w0.w}, {w1.x, w1.y, w1.z, w1.w}};
        #pragma unroll
        for (int ri = 0; ri < 2; ++ri)
            #pragma unroll
            for (int i = 0; i < 4; ++i)
                #pragma unroll
                for (int ci = 0; ci < 2; ++ci)
                    #pragma unroll
                    for (int j = 0; j < 4; ++j)
                        acc[ri][ci][i][j] += av[ri][i] * wv[ci][j];
    }
    __syncthreads();   // all RA/RX reads done

    // ---- write XAT[d][n] (stride 132) into RX; stage W1[k][c] into RA ----
    #pragma unroll
    for (int ci = 0; ci < 2; ++ci)
        #pragma unroll
        for (int j = 0; j < 4; ++j) {
            int d = (ci ? 64 : 0) + 4 * tx + j;
            float4 v0 = make_float4(acc[0][ci][0][j], acc[0][ci][1][j], acc[0][ci][2][j], acc[0][ci][3][j]);
            float4 v1 = make_float4(acc[1][ci][0][j], acc[1][ci][1][j], acc[1][ci][2][j], acc[1][ci][3][j]);
            *(float4*)(RX + d * 132 + 4 * ty) = v0;
            *(float4*)(RX + d * 132 + 64 + 4 * ty) = v1;
        }
    #pragma unroll
    for (int i = 0; i < 16; ++i) {
        int c = t + i * 256;
        int row = c >> 5, col4 = (c & 31) << 2;
        *(float4*)(RA + row * 132 + col4) = ((const float4*)W1)[c];
    }
    __syncthreads();

    // ---- phase 2: h = relu(XA @ W1 + b1) ----
    #pragma unroll
    for (int ri = 0; ri < 2; ++ri)
        #pragma unroll
        for (int ci = 0; ci < 2; ++ci)
            #pragma unroll
            for (int i = 0; i < 4; ++i)
                #pragma unroll
                for (int j = 0; j < 4; ++j) acc[ri][ci][i][j] = 0.f;

    #pragma unroll 4
    for (int k = 0; k < 128; ++k) {
        float4 a0 = *(const float4*)(RX + k * 132 + 4 * ty);        // XAT[k][node]
        float4 a1 = *(const float4*)(RX + k * 132 + 64 + 4 * ty);
        float4 w0 = *(const float4*)(RA + k * 132 + 4 * tx);        // W1[k][col]
        float4 w1 = *(const float4*)(RA + k * 132 + 64 + 4 * tx);
        float av[2][4] = {{a0.x, a0.y, a0.z, a0.w}, {a1.x, a1.y, a1.z, a1.w}};
        float wv[2][4] = {{w0.x, w0.y, w0.z, w0.w}, {w1.x, w1.y, w1.z, w1.w}};
        #pragma unroll
        for (int ri = 0; ri < 2; ++ri)
            #pragma unroll
            for (int i = 0; i < 4; ++i)
                #pragma unroll
                for (int ci = 0; ci < 2; ++ci)
                    #pragma unroll
                    for (int j = 0; j < 4; ++j)
                        acc[ri][ci][i][j] += av[ri][i] * wv[ci][j];
    }
    __syncthreads();   // XAT / W1 reads done

    // ---- relu+bias, write HT[c][n] (stride 132) into RA; stage WB into RX ----
    {
        float4 bq0 = *(const float4*)(b1 + 4 * tx);
        float4 bq1 = *(const float4*)(b1 + 64 + 4 * tx);
        float bb[2][4] = {{bq0.x, bq0.y, bq0.z, bq0.w}, {bq1.x, bq1.y, bq1.z, bq1.w}};
        #pragma unroll
        for (int ci = 0; ci < 2; ++ci)
            #pragma unroll
            for (int j = 0; j < 4; ++j) {
                int c = (ci ? 64 : 0) + 4 * tx + j;
                float4 v0, v1;
                v0.x = fmaxf(acc[0][ci][0][j] + bb[ci][j], 0.f);
                v0.y = fmaxf(acc[0][ci][1][j] + bb[ci][j], 0.f);
                v0.z = fmaxf(acc[0][ci][2][j] + bb[ci][j], 0.f);
                v0.w = fmaxf(acc[0][ci][3][j] + bb[ci][j], 0.f);
                v1.x = fmaxf(acc[1][ci][0][j] + bb[ci][j], 0.f);
                v1.y = fmaxf(acc[1][ci][1][j] + bb[ci][j], 0.f);
                v1.z = fmaxf(acc[1][ci][2][j] + bb[ci][j], 0.f);
                v1.w = fmaxf(acc[1][ci][3][j] + bb[ci][j], 0.f);
                *(float4*)(RA + c * 132 + 4 * ty) = v0;
                *(float4*)(RA + c * 132 + 64 + 4 * ty) = v1;
            }
    }
    #pragma unroll
    for (int i = 0; i < 8; ++i) {
        int c = t + i * 256;                  // 2048 float4: WB[k][64] = [Wmu|Wls]
        int row = c >> 4, q = c & 15;
        float4 v = (q < 8) ? *(const float4*)(Wmu + row * 32 + 4 * q)
                           : *(const float4*)(Wls + row * 32 + 4 * (q - 8));
        *(float4*)(RX + row * 64 + 4 * q) = v;
    }
    __syncthreads();

    // ---- phase 3: [mu|ls] = h @ WB + bias  (128 x 64) ----
    float acc3[2][4][4];
    #pragma unroll
    for (int ri = 0; ri < 2; ++ri)
        #pragma unroll
        for (int i = 0; i < 4; ++i)
            #pragma unroll
            for (int j = 0; j < 4; ++j) acc3[ri][i][j] = 0.f;

    #pragma unroll 4
    for (int k = 0; k < 128; ++k) {
        float4 h0 = *(const float4*)(RA + k * 132 + 4 * ty);
        float4 h1 = *(const float4*)(RA + k * 132 + 64 + 4 * ty);
        float4 w  = *(const float4*)(RX + k * 64 + 4 * tx);
        float hv[2][4] = {{h0.x, h0.y, h0.z, h0.w}, {h1.x, h1.y, h1.z, h1.w}};
        float wv[4] = {w.x, w.y, w.z, w.w};
        #pragma unroll
        for (int ri = 0; ri < 2; ++ri)
            #pragma unroll
            for (int i = 0; i < 4; ++i)
                #pragma unroll
                for (int j = 0; j < 4; ++j)
                    acc3[ri][i][j] += hv[ri][i] * wv[j];
    }
    // MLS writes go to RX[8192..16896) — disjoint from WB reads, no barrier needed yet
    {
        float4 bv = (tx < 8) ? *(const float4*)(bmu + 4 * tx)
                             : *(const float4*)(bls + 4 * tx - 32);
        float bb[4] = {bv.x, bv.y, bv.z, bv.w};
        #pragma unroll
        for (int ri = 0; ri < 2; ++ri)
            #pragma unroll
            for (int i = 0; i < 4; ++i) {
                int n = (ri ? 64 : 0) + 4 * ty + i;
                float4 v = make_float4(acc3[ri][i][0] + bb[0], acc3[ri][i][1] + bb[1],
                                       acc3[ri][i][2] + bb[2], acc3[ri][i][3] + bb[3]);
                *(float4*)(RX + 8192 + n * 68 + 4 * tx) = v;
            }
    }
    __syncthreads();   // MLS visible; HT (RA) dead -> reuse RA for ZT

    // ---- phase 4: z = mu + exp(ls)*eps, KL; ZT[l][n] (stride 132) into RA ----
    {
        const float* MLS = RX + 8192;
        int n = t & 127, half = t >> 7;
        float klp = 0.f;
        #pragma unroll
        for (int k4 = 0; k4 < 4; ++k4) {
            int l = half * 16 + k4 * 4;
            float4 mu = *(const float4*)(MLS + n * 68 + l);
            float4 lsv = *(const float4*)(MLS + n * 68 + 32 + l);
            float4 ev = *(const float4*)(eps + (size_t)(gbase + n) * L_ + l);
            float sx = expf(lsv.x), sy = expf(lsv.y), sz = expf(lsv.z), sw = expf(lsv.w);
            RA[(l + 0) * 132 + n] = mu.x + sx * ev.x;
            RA[(l + 1) * 132 + n] = mu.y + sy * ev.y;
            RA[(l + 2) * 132 + n] = mu.z + sz * ev.z;
            RA[(l + 3) * 132 + n] = mu.w + sw * ev.w;
            klp += (sx * sx + mu.x * mu.x - 1.f - 2.f * lsv.x)
                 + (sy * sy + mu.y * mu.y - 1.f - 2.f * lsv.y)
                 + (sz * sz + mu.z * mu.z - 1.f - 2.f * lsv.z)
                 + (sw * sw + mu.w * mu.w - 1.f - 2.f * lsv.w);
        }
        RED[t] = klp;
    }
    __syncthreads();
    for (int s = 128; s > 0; s >>= 1) { if (t < s) RED[t] += RED[t + s]; __syncthreads(); }
    if (t == 0) sKL = RED[0];
    __syncthreads();

    // ---- phase 5: Gram decoder: logits = Z Z^T, masked softplus sum ----
    float g4[2][2][4][4];
    #pragma unroll
    for (int ri = 0; ri < 2; ++ri)
        #pragma unroll
        for (int ci = 0; ci < 2; ++ci)
            #pragma unroll
            for (int i = 0; i < 4; ++i)
                #pragma unroll
                for (int j = 0; j < 4; ++j) g4[ri][ci][i][j] = 0.f;

    #pragma unroll 4
    for (int k = 0; k < 32; ++k) {
        float4 a0 = *(const float4*)(RA + k * 132 + 4 * ty);
        float4 a1 = *(const float4*)(RA + k * 132 + 64 + 4 * ty);
        float4 w0 = *(const float4*)(RA + k * 132 + 4 * tx);
        float4 w1 = *(const float4*)(RA + k * 132 + 64 + 4 * tx);
        float av[2][4] = {{a0.x, a0.y, a0.z, a0.w}, {a1.x, a1.y, a1.z, a1.w}};
        float wv[2][4] = {{w0.x, w0.y, w0.z, w0.w}, {w1.x, w1.y, w1.z, w1.w}};
        #pragma unroll
        for (int ri = 0; ri < 2; ++ri)
            #pragma unroll
            for (int i = 0; i < 4; ++i)
                #pragma unroll
                for (int ci = 0; ci < 2; ++ci)
                    #pragma unroll
                    for (int j = 0; j < 4; ++j)
                        g4[ri][ci][i][j] += av[ri][i] * wv[ci][j];
    }
    {
        float lp = 0.f;
        #pragma unroll
        for (int ri = 0; ri < 2; ++ri)
            #pragma unroll
            for (int i2 = 0; i2 < 4; ++i2) {
                int i = (ri ? 64 : 0) + 4 * ty + i2;
                #pragma unroll
                for (int ci = 0; ci < 2; ++ci)
                    #pragma unroll
                    for (int j2 = 0; j2 < 4; ++j2) {
                        int j = (ci ? 64 : 0) + 4 * tx + j2;
                        if (j > i) {
                            float lg = g4[ri][ci][i2][j2];
                            int p = i * (255 - i) / 2 + (j - i - 1);
                            unsigned bit = (BM[p >> 5] >> (p & 31)) & 1u;
                            float sp = log1pf(expf(-fabsf(lg))) + fmaxf(lg, 0.f);
                            lp += bit ? (lg - sp) : (-sp);
                        }
                    }
            }
        RED[t] = lp;
    }
    __syncthreads();
    for (int s = 128; s > 0; s >>= 1) { if (t < s) RED[t] += RED[t + s]; __syncthreads(); }
    if (t == 0) res[b] = 0.5f * sKL - RED[0];
}

// ---------------------------------------------------------------------------
__global__ __launch_bounds__(256) void k_finalize(
    const float* __restrict__ res, float* __restrict__ out)
{
    __shared__ float RED[256];
    int t = threadIdx.x;
    RED[t] = res[t];
    __syncthreads();
    for (int s = 128; s > 0; s >>= 1) {
        if (t < s) RED[t] += RED[t + s];
        __syncthreads();
    }
    if (t == 0) out[0] = RED[0] * (1.0f / 256.0f);
}

// ---------------------------------------------------------------------------
extern "C" void kernel_launch(void* const* d_in, const int* in_sizes, int n_in,
                              void* d_out, int out_size, void* d_ws, size_t ws_size,
                              hipStream_t stream) {
    const float* x   = (const float*)d_in[0];
    const int*   ei  = (const int*)d_in[1];
    // d_in[2] = batch (unused; block-contiguous layout known)
    const float* eps = (const float*)d_in[3];
    const float* W1  = (const float*)d_in[4];
    const float* b1  = (const float*)d_in[5];
    const float* Wmu = (const float*)d_in[6];
    const float* bmu = (const float*)d_in[7];
    const float* Wls = (const float*)d_in[8];
    const float* bls = (const float*)d_in[9];

    unsigned* cnt  = (unsigned*)d_ws;
    unsigned* ebuf = cnt + EBUF_OFF;
    float*    res  = (float*)((unsigned*)d_ws + RES_OFF);

    hipMemsetAsync(d_ws, 0, 256 * sizeof(unsigned), stream);  // cnt only

    k_bucket  <<<E_ / 256, 256, 0, stream>>>(ei, cnt, ebuf);
    k_graph   <<<B_, 256, 0, stream>>>(x, eps, W1, b1, Wmu, bmu, Wls, bls,
                                       cnt, ebuf, res);
    k_finalize<<<1, 256, 0, stream>>>(res, (float*)d_out);
}

// Round 3
// 225.903 us; speedup vs baseline: 4.5765x; 1.1815x over previous
//
#include <hip/hip_runtime.h>
#include <math.h>

#define B_ 256
#define N_ 128
#define D_ 128
#define L_ 32
#define E_ 262144
#define PW_ 254          // bitmap words per graph = 8128/32
#define DCAP 96          // per-node neighbor capacity (max deg ~70 expected)

// workspace layout (u32 units)
#define NDEG_OFF 0               // 32768 u32 per-node degree counters
#define BM_OFF   32768           // 65024 u32 pair-target bitmap
#define KLS_OFF  97792           // 256 f32 per-graph KL sums
#define RES_OFF  98048           // 256 f32 per-graph (kls - log_probs)
#define ADJ_OFF  98304           // 32768*96 u8 CSR neighbor lists (786432 u32)
#define XA_OFF   884736          // 32768*128 f32 aggregated features
#define Z_OFF    5079040         // 32768*32 f32 latents
#define ZERO_WORDS 98048         // ndeg + bitmap + kls

// ---------------------------------------------------------------------------
// Per-edge: CSR adjacency build (atomics over 32768 node counters) + bitmap.
__global__ __launch_bounds__(256) void k_build(
    const int* __restrict__ ei, unsigned* __restrict__ ndeg,
    unsigned char* __restrict__ adj, unsigned* __restrict__ bm)
{
    int e = blockIdx.x * 256 + threadIdx.x;
    int src = ei[e], dst = ei[E_ + e];
    unsigned s1 = atomicAdd(&ndeg[src], 1u);
    if (s1 < DCAP) adj[(size_t)src * DCAP + s1] = (unsigned char)(dst & 127);
    unsigned s2 = atomicAdd(&ndeg[dst], 1u);
    if (s2 < DCAP) adj[(size_t)dst * DCAP + s2] = (unsigned char)(src & 127);
    int li = src & 127, lj = dst & 127, g = src >> 7;
    int p = li * (255 - li) / 2 + (lj - li - 1);
    atomicOr(&bm[g * PW_ + (p >> 5)], 1u << (p & 31));
}

// ---------------------------------------------------------------------------
// Per-graph wave-cooperative gather: XA[n] = X[n] + sum_{m in nbr(n)} X[m].
// Wave w handles nodes w*32..w*32+31; lane halves process alternate neighbors;
// 32 lanes x float4 = one full conflict-free 512B row read per neighbor.
__global__ __launch_bounds__(256) void k_aggregate(
    const float* __restrict__ x, const unsigned* __restrict__ ndeg,
    const unsigned char* __restrict__ adj, float* __restrict__ xa)
{
    __shared__ float Xs[128 * 128];          // 64 KB
    __shared__ unsigned char ADJ[128 * DCAP]; // 12 KB
    __shared__ unsigned DEG[128];
    int t = threadIdx.x, b = blockIdx.x, gbase = b << 7;

    #pragma unroll
    for (int i = 0; i < 16; ++i) {
        int c = t + i * 256;
        ((float4*)Xs)[c] = ((const float4*)(x + (size_t)gbase * 128))[c];
    }
    #pragma unroll
    for (int i = 0; i < 12; ++i) {
        int c = t + i * 256;                 // 3072 u32 = 128*96 bytes
        ((unsigned*)ADJ)[c] = ((const unsigned*)(adj + (size_t)gbase * DCAP))[c];
    }
    if (t < 128) { unsigned d = ndeg[gbase + t]; DEG[t] = d > DCAP ? DCAP : d; }
    __syncthreads();

    int lane = t & 63, w = t >> 6, half = lane >> 5, q = lane & 31;
    for (int nn = 0; nn < 32; ++nn) {
        int n = w * 32 + nn;
        int deg = (int)DEG[n];
        float4 acc;
        if (half == 0) acc = *(const float4*)(Xs + n * 128 + 4 * q);
        else           acc = make_float4(0.f, 0.f, 0.f, 0.f);
        for (int e = half; e < deg; e += 2) {
            int m = (int)ADJ[n * DCAP + e];
            float4 v = *(const float4*)(Xs + m * 128 + 4 * q);
            acc.x += v.x; acc.y += v.y; acc.z += v.z; acc.w += v.w;
        }
        float4 oth;
        oth.x = __shfl_xor(acc.x, 32);
        oth.y = __shfl_xor(acc.y, 32);
        oth.z = __shfl_xor(acc.z, 32);
        oth.w = __shfl_xor(acc.w, 32);
        if (half == 0) {
            float4 r = make_float4(acc.x + oth.x, acc.y + oth.y,
                                   acc.z + oth.z, acc.w + oth.w);
            *(float4*)(xa + (size_t)(gbase + n) * 128 + 4 * q) = r;
        }
    }
}

// ---------------------------------------------------------------------------
// Row-local encoder: block = 64 rows. GEMM1 (64x128 @ 128x128, W1 in k-halves),
// relu, GEMM2 (64x128 @ 128x64 [Wmu|Wls]), z = mu+exp(ls)*eps, KL atomics.
// 67 KB LDS -> 2 blocks/CU. A-operand LDS reads are broadcasts (VALU-bound).
__global__ __launch_bounds__(256) void k_encoder(
    const float* __restrict__ xa, const float* __restrict__ W1,
    const float* __restrict__ b1, const float* __restrict__ Wmu,
    const float* __restrict__ bmu, const float* __restrict__ Wls,
    const float* __restrict__ bls, const float* __restrict__ eps,
    float* __restrict__ z, float* __restrict__ kls)
{
    __shared__ float XAs[64 * 132];   // 33792 B; later reused as HS
    __shared__ float Ws[8192];        // 32768 B; W1 k-half, later WB [128][64]
    __shared__ float RED[256];
    int t = threadIdx.x;
    int row0 = blockIdx.x * 64;
    int g = blockIdx.x >> 1;
    int ty = t >> 4, tx = t & 15;

    #pragma unroll
    for (int i = 0; i < 8; ++i) {
        int c = t + i * 256;          // 2048 float4 = 64x128
        int n = c >> 5, d4 = (c & 31) << 2;
        *(float4*)(XAs + n * 132 + d4) = *(const float4*)(xa + (size_t)(row0 + n) * 128 + d4);
    }

    float acc[4][8];
    #pragma unroll
    for (int i = 0; i < 4; ++i)
        #pragma unroll
        for (int j = 0; j < 8; ++j) acc[i][j] = 0.f;

    for (int kh = 0; kh < 2; ++kh) {
        __syncthreads();              // XAs staged / prior Ws reads done
        #pragma unroll
        for (int i = 0; i < 8; ++i) {
            int c = t + i * 256;      // 2048 float4 = 64x128 W1 rows
            ((float4*)Ws)[c] = ((const float4*)(W1 + kh * 8192))[c];
        }
        __syncthreads();
        #pragma unroll 4
        for (int k = 0; k < 64; ++k) {
            int kk = kh * 64 + k;
            float a0 = XAs[(4 * ty + 0) * 132 + kk];
            float a1 = XAs[(4 * ty + 1) * 132 + kk];
            float a2 = XAs[(4 * ty + 2) * 132 + kk];
            float a3 = XAs[(4 * ty + 3) * 132 + kk];
            float4 w0 = *(const float4*)(Ws + k * 128 + 8 * tx);
            float4 w1 = *(const float4*)(Ws + k * 128 + 8 * tx + 4);
            float av[4] = {a0, a1, a2, a3};
            float wv[8] = {w0.x, w0.y, w0.z, w0.w, w1.x, w1.y, w1.z, w1.w};
            #pragma unroll
            for (int i = 0; i < 4; ++i)
                #pragma unroll
                for (int j = 0; j < 8; ++j) acc[i][j] += av[i] * wv[j];
        }
    }
    __syncthreads();

    // relu + b1 -> HS (XAs region); stage WB = [Wmu|Wls] into Ws
    {
        float4 bb0 = *(const float4*)(b1 + 8 * tx);
        float4 bb1 = *(const float4*)(b1 + 8 * tx + 4);
        float bb[8] = {bb0.x, bb0.y, bb0.z, bb0.w, bb1.x, bb1.y, bb1.z, bb1.w};
        #pragma unroll
        for (int i = 0; i < 4; ++i) {
            float4 h0, h1;
            h0.x = fmaxf(acc[i][0] + bb[0], 0.f);
            h0.y = fmaxf(acc[i][1] + bb[1], 0.f);
            h0.z = fmaxf(acc[i][2] + bb[2], 0.f);
            h0.w = fmaxf(acc[i][3] + bb[3], 0.f);
            h1.x = fmaxf(acc[i][4] + bb[4], 0.f);
            h1.y = fmaxf(acc[i][5] + bb[5], 0.f);
            h1.z = fmaxf(acc[i][6] + bb[6], 0.f);
            h1.w = fmaxf(acc[i][7] + bb[7], 0.f);
            *(float4*)(XAs + (4 * ty + i) * 132 + 8 * tx)     = h0;
            *(float4*)(XAs + (4 * ty + i) * 132 + 8 * tx + 4) = h1;
        }
    }
    #pragma unroll
    for (int i = 0; i < 8; ++i) {
        int c = t + i * 256;          // 2048 float4 = 128x64 WB
        int row = c >> 4, col4 = (c & 15) << 2;
        float4 v = (col4 < 32) ? *(const float4*)(Wmu + row * 32 + col4)
                               : *(const float4*)(Wls + row * 32 + col4 - 32);
        *(float4*)(Ws + row * 64 + col4) = v;
    }
    __syncthreads();

    // GEMM2: [mu|ls] = h @ WB  (64 x 64), 4x4 per thread
    float a2c[4][4];
    #pragma unroll
    for (int i = 0; i < 4; ++i)
        #pragma unroll
        for (int j = 0; j < 4; ++j) a2c[i][j] = 0.f;
    #pragma unroll 4
    for (int k = 0; k < 128; ++k) {
        float h0 = XAs[(4 * ty + 0) * 132 + k];
        float h1 = XAs[(4 * ty + 1) * 132 + k];
        float h2 = XAs[(4 * ty + 2) * 132 + k];
        float h3 = XAs[(4 * ty + 3) * 132 + k];
        float4 wv = *(const float4*)(Ws + k * 64 + 4 * tx);
        float hv[4] = {h0, h1, h2, h3};
        float wa[4] = {wv.x, wv.y, wv.z, wv.w};
        #pragma unroll
        for (int i = 0; i < 4; ++i)
            #pragma unroll
            for (int j = 0; j < 4; ++j) a2c[i][j] += hv[i] * wa[j];
    }
    {
        float4 bv = (tx < 8) ? *(const float4*)(bmu + 4 * tx)
                             : *(const float4*)(bls + 4 * (tx - 8));
        float ba[4] = {bv.x, bv.y, bv.z, bv.w};
        #pragma unroll
        for (int i = 0; i < 4; ++i)
            #pragma unroll
            for (int j = 0; j < 4; ++j) a2c[i][j] += ba[j];
    }
    // exchange mu<->ls with partner lane (tx ^ 8)
    float oth[4][4];
    #pragma unroll
    for (int i = 0; i < 4; ++i)
        #pragma unroll
        for (int j = 0; j < 4; ++j) oth[i][j] = __shfl_xor(a2c[i][j], 8);

    // epilogue: tx<8 handles rows {0,1}, tx>=8 rows {2,3}; l = 4*(tx&7)
    float klsum = 0.f;
    {
        int i0 = (tx < 8) ? 0 : 2;
        int l0 = 4 * (tx & 7);
        #pragma unroll
        for (int ii = 0; ii < 2; ++ii) {
            int i = i0 + ii;
            int rowg = row0 + 4 * ty + i;
            float mu[4], lsv[4];
            #pragma unroll
            for (int j = 0; j < 4; ++j) {
                mu[j]  = (tx < 8) ? a2c[i][j] : oth[i][j];
                lsv[j] = (tx < 8) ? oth[i][j] : a2c[i][j];
            }
            float4 ev = *(const float4*)(eps + (size_t)rowg * 32 + l0);
            float ea[4] = {ev.x, ev.y, ev.z, ev.w};
            float4 zv;
            float zz[4];
            #pragma unroll
            for (int j = 0; j < 4; ++j) {
                float s = expf(lsv[j]);
                zz[j] = mu[j] + s * ea[j];
                klsum += s * s + mu[j] * mu[j] - 1.f - 2.f * lsv[j];
            }
            zv.x = zz[0]; zv.y = zz[1]; zv.z = zz[2]; zv.w = zz[3];
            *(float4*)(z + (size_t)rowg * 32 + l0) = zv;
        }
    }
    RED[t] = klsum;
    __syncthreads();
    for (int s = 128; s > 0; s >>= 1) {
        if (t < s) RED[t] += RED[t + s];
        __syncthreads();
    }
    if (t == 0) atomicAdd(&kls[g], 0.5f * RED[0]);
}

// ---------------------------------------------------------------------------
// Decoder: one block per graph. Full 128x128 Gram via 8x8 register tiles,
// softplus + bitmap-target on upper triangle, block-reduce -> res[b].
__global__ __launch_bounds__(256) void k_decoder(
    const float* __restrict__ z, const unsigned* __restrict__ bitmap,
    const float* __restrict__ kls, float* __restrict__ res)
{
    __shared__ float zT[32 * 132];
    __shared__ unsigned bm[PW_];
    __shared__ float RED[256];
    int b = blockIdx.x, t = threadIdx.x;

    #pragma unroll
    for (int i = 0; i < 16; ++i) {
        int c = t + i * 256;
        int n = c >> 5, l = c & 31;
        zT[l * 132 + n] = z[((size_t)b * N_ + n) * L_ + l];
    }
    if (t < PW_) bm[t] = bitmap[b * PW_ + t];
    __syncthreads();

    int i0 = (t >> 4) << 3;
    int j0 = (t & 15) << 3;
    float g[8][8];
    #pragma unroll
    for (int a = 0; a < 8; ++a)
        #pragma unroll
        for (int c = 0; c < 8; ++c) g[a][c] = 0.f;

    #pragma unroll 4
    for (int l = 0; l < 32; ++l) {
        float4 a0 = *(const float4*)(zT + l * 132 + i0);
        float4 a1 = *(const float4*)(zT + l * 132 + i0 + 4);
        float4 b0 = *(const float4*)(zT + l * 132 + j0);
        float4 b1v = *(const float4*)(zT + l * 132 + j0 + 4);
        float za[8] = {a0.x, a0.y, a0.z, a0.w, a1.x, a1.y, a1.z, a1.w};
        float zb[8] = {b0.x, b0.y, b0.z, b0.w, b1v.x, b1v.y, b1v.z, b1v.w};
        #pragma unroll
        for (int a = 0; a < 8; ++a)
            #pragma unroll
            for (int c = 0; c < 8; ++c) g[a][c] += za[a] * zb[c];
    }

    float sum = 0.f;
    #pragma unroll
    for (int a = 0; a < 8; ++a) {
        int i = i0 + a;
        #pragma unroll
        for (int c = 0; c < 8; ++c) {
            int j = j0 + c;
            if (j > i) {
                float lg = g[a][c];
                int p = i * (255 - i) / 2 + (j - i - 1);
                unsigned bit = (bm[p >> 5] >> (p & 31)) & 1u;
                float sp = log1pf(expf(-fabsf(lg))) + fmaxf(lg, 0.f);
                sum += bit ? (lg - sp) : (-sp);
            }
        }
    }
    RED[t] = sum;
    __syncthreads();
    for (int s = 128; s > 0; s >>= 1) {
        if (t < s) RED[t] += RED[t + s];
        __syncthreads();
    }
    if (t == 0) res[b] = kls[b] - RED[0];
}

// ---------------------------------------------------------------------------
__global__ __launch_bounds__(256) void k_finalize(
    const float* __restrict__ res, float* __restrict__ out)
{
    __shared__ float RED[256];
    int t = threadIdx.x;
    RED[t] = res[t];
    __syncthreads();
    for (int s = 128; s > 0; s >>= 1) {
        if (t < s) RED[t] += RED[t + s];
        __syncthreads();
    }
    if (t == 0) out[0] = RED[0] * (1.0f / 256.0f);
}

// ---------------------------------------------------------------------------
extern "C" void kernel_launch(void* const* d_in, const int* in_sizes, int n_in,
                              void* d_out, int out_size, void* d_ws, size_t ws_size,
                              hipStream_t stream) {
    const float* x   = (const float*)d_in[0];
    const int*   ei  = (const int*)d_in[1];
    // d_in[2] = batch (unused; block-contiguous layout known)
    const float* eps = (const float*)d_in[3];
    const float* W1  = (const float*)d_in[4];
    const float* b1  = (const float*)d_in[5];
    const float* Wmu = (const float*)d_in[6];
    const float* bmu = (const float*)d_in[7];
    const float* Wls = (const float*)d_in[8];
    const float* bls = (const float*)d_in[9];

    unsigned* wsw = (unsigned*)d_ws;
    unsigned*      ndeg = wsw + NDEG_OFF;
    unsigned*      bm   = wsw + BM_OFF;
    float*         kls  = (float*)(wsw + KLS_OFF);
    float*         res  = (float*)(wsw + RES_OFF);
    unsigned char* adj  = (unsigned char*)(wsw + ADJ_OFF);
    float*         xa   = (float*)(wsw + XA_OFF);
    float*         z    = (float*)(wsw + Z_OFF);

    hipMemsetAsync(d_ws, 0, ZERO_WORDS * sizeof(unsigned), stream);

    k_build    <<<E_ / 256, 256, 0, stream>>>(ei, ndeg, adj, bm);
    k_aggregate<<<B_, 256, 0, stream>>>(x, ndeg, adj, xa);
    k_encoder  <<<512, 256, 0, stream>>>(xa, W1, b1, Wmu, bmu, Wls, bls,
                                         eps, z, kls);
    k_decoder  <<<B_, 256, 0, stream>>>(z, bm, kls, res);
    k_finalize <<<1, 256, 0, stream>>>(res, (float*)d_out);
}

// Round 4
// 212.192 us; speedup vs baseline: 4.8722x; 1.0646x over previous
//
#include <hip/hip_runtime.h>
#include <math.h>

#define B_ 256
#define N_ 128
#define D_ 128
#define L_ 32
#define E_ 262144
#define PW_ 254          // bitmap words per graph = 8128/32
#define DCAP 96          // per-node neighbor capacity (max deg ~70 expected)

// workspace layout (u32 units)
#define NDEG_OFF 0               // 32768 u32 per-node degree counters
#define BM_OFF   32768           // 65024 u32 pair-target bitmap
#define KLS_OFF  97792           // 256 f32 per-graph KL sums
#define LP_OFF   98048           // 256 f32 per-graph log_prob sums
#define ADJ_OFF  98304           // 32768*96 u8 CSR neighbor lists (786432 u32)
#define XA_OFF   884736          // 32768*128 f32 aggregated features
#define Z_OFF    5079040         // 32768*32 f32 latents
#define ZERO_WORDS 98304         // ndeg + bitmap + kls + logp

// ---------------------------------------------------------------------------
// Per-edge: CSR adjacency build (atomics over 32768 node counters) + bitmap.
__global__ __launch_bounds__(256) void k_build(
    const int* __restrict__ ei, unsigned* __restrict__ ndeg,
    unsigned char* __restrict__ adj, unsigned* __restrict__ bm)
{
    int e = blockIdx.x * 256 + threadIdx.x;
    int src = ei[e], dst = ei[E_ + e];
    unsigned s1 = atomicAdd(&ndeg[src], 1u);
    if (s1 < DCAP) adj[(size_t)src * DCAP + s1] = (unsigned char)(dst & 127);
    unsigned s2 = atomicAdd(&ndeg[dst], 1u);
    if (s2 < DCAP) adj[(size_t)dst * DCAP + s2] = (unsigned char)(src & 127);
    int li = src & 127, lj = dst & 127, g = src >> 7;
    int p = li * (255 - li) / 2 + (lj - li - 1);
    atomicOr(&bm[g * PW_ + (p >> 5)], 1u << (p & 31));
}

// ---------------------------------------------------------------------------
// Global-gather aggregate: XA[n] = X[n] + sum_{m in nbr(n)} X[m].
// 16 nodes/block, 16 threads/node (8 floats each). Neighbor indices
// prefetched 4-at-a-time (packed u32) -> 8 independent float4 loads in
// flight per step. X rows come from L2/L3 (per-graph X = 64 KB, hot).
__global__ __launch_bounds__(256) void k_aggregate(
    const float* __restrict__ x, const unsigned* __restrict__ ndeg,
    const unsigned char* __restrict__ adj, float* __restrict__ xa)
{
    int t = threadIdx.x;
    int grp = t >> 4;                       // 16 node-groups per block
    int l16 = t & 15;                       // 8 floats per thread
    int gnode = blockIdx.x * 16 + grp;      // 0..32767
    int gb = gnode & ~127;                  // graph base node
    int fo = l16 * 8;

    const float* xr = x + (size_t)gnode * 128 + fo;
    float4 a0 = *(const float4*)xr;
    float4 a1 = *(const float4*)(xr + 4);

    int deg = (int)ndeg[gnode];
    if (deg > DCAP) deg = DCAP;
    const unsigned char* al = adj + (size_t)gnode * DCAP;

    int e = 0;
    for (; e + 4 <= deg; e += 4) {
        unsigned pk = *(const unsigned*)(al + e);   // al is 32B-aligned, e%4==0
        int m0 = (int)(pk & 255u);
        int m1 = (int)((pk >> 8) & 255u);
        int m2 = (int)((pk >> 16) & 255u);
        int m3 = (int)(pk >> 24);
        const float* r0 = x + (size_t)(gb + m0) * 128 + fo;
        const float* r1 = x + (size_t)(gb + m1) * 128 + fo;
        const float* r2 = x + (size_t)(gb + m2) * 128 + fo;
        const float* r3 = x + (size_t)(gb + m3) * 128 + fo;
        float4 v00 = *(const float4*)r0, v01 = *(const float4*)(r0 + 4);
        float4 v10 = *(const float4*)r1, v11 = *(const float4*)(r1 + 4);
        float4 v20 = *(const float4*)r2, v21 = *(const float4*)(r2 + 4);
        float4 v30 = *(const float4*)r3, v31 = *(const float4*)(r3 + 4);
        a0.x += v00.x + v10.x + v20.x + v30.x;
        a0.y += v00.y + v10.y + v20.y + v30.y;
        a0.z += v00.z + v10.z + v20.z + v30.z;
        a0.w += v00.w + v10.w + v20.w + v30.w;
        a1.x += v01.x + v11.x + v21.x + v31.x;
        a1.y += v01.y + v11.y + v21.y + v31.y;
        a1.z += v01.z + v11.z + v21.z + v31.z;
        a1.w += v01.w + v11.w + v21.w + v31.w;
    }
    for (; e < deg; ++e) {
        int m = (int)al[e];
        const float* r = x + (size_t)(gb + m) * 128 + fo;
        float4 v0 = *(const float4*)r, v1 = *(const float4*)(r + 4);
        a0.x += v0.x; a0.y += v0.y; a0.z += v0.z; a0.w += v0.w;
        a1.x += v1.x; a1.y += v1.y; a1.z += v1.z; a1.w += v1.w;
    }
    float* o = xa + (size_t)gnode * 128 + fo;
    *(float4*)o = a0;
    *(float4*)(o + 4) = a1;
}

// ---------------------------------------------------------------------------
// Row-local encoder: block = 64 rows. GEMM1 (64x128 @ 128x128, W1 in k-halves),
// relu, GEMM2 (64x128 @ 128x64 [Wmu|Wls]), z = mu+exp(ls)*eps, KL atomics.
__global__ __launch_bounds__(256) void k_encoder(
    const float* __restrict__ xa, const float* __restrict__ W1,
    const float* __restrict__ b1, const float* __restrict__ Wmu,
    const float* __restrict__ bmu, const float* __restrict__ Wls,
    const float* __restrict__ bls, const float* __restrict__ eps,
    float* __restrict__ z, float* __restrict__ kls)
{
    __shared__ float XAs[64 * 132];   // 33792 B; later reused as HS
    __shared__ float Ws[8192];        // 32768 B; W1 k-half, later WB [128][64]
    __shared__ float RED[256];
    int t = threadIdx.x;
    int row0 = blockIdx.x * 64;
    int g = blockIdx.x >> 1;
    int ty = t >> 4, tx = t & 15;

    #pragma unroll
    for (int i = 0; i < 8; ++i) {
        int c = t + i * 256;          // 2048 float4 = 64x128
        int n = c >> 5, d4 = (c & 31) << 2;
        *(float4*)(XAs + n * 132 + d4) = *(const float4*)(xa + (size_t)(row0 + n) * 128 + d4);
    }

    float acc[4][8];
    #pragma unroll
    for (int i = 0; i < 4; ++i)
        #pragma unroll
        for (int j = 0; j < 8; ++j) acc[i][j] = 0.f;

    for (int kh = 0; kh < 2; ++kh) {
        __syncthreads();
        #pragma unroll
        for (int i = 0; i < 8; ++i) {
            int c = t + i * 256;
            ((float4*)Ws)[c] = ((const float4*)(W1 + kh * 8192))[c];
        }
        __syncthreads();
        #pragma unroll 4
        for (int k = 0; k < 64; ++k) {
            int kk = kh * 64 + k;
            float a0 = XAs[(4 * ty + 0) * 132 + kk];
            float a1 = XAs[(4 * ty + 1) * 132 + kk];
            float a2 = XAs[(4 * ty + 2) * 132 + kk];
            float a3 = XAs[(4 * ty + 3) * 132 + kk];
            float4 w0 = *(const float4*)(Ws + k * 128 + 8 * tx);
            float4 w1 = *(const float4*)(Ws + k * 128 + 8 * tx + 4);
            float av[4] = {a0, a1, a2, a3};
            float wv[8] = {w0.x, w0.y, w0.z, w0.w, w1.x, w1.y, w1.z, w1.w};
            #pragma unroll
            for (int i = 0; i < 4; ++i)
                #pragma unroll
                for (int j = 0; j < 8; ++j) acc[i][j] += av[i] * wv[j];
        }
    }
    __syncthreads();

    {
        float4 bb0 = *(const float4*)(b1 + 8 * tx);
        float4 bb1 = *(const float4*)(b1 + 8 * tx + 4);
        float bb[8] = {bb0.x, bb0.y, bb0.z, bb0.w, bb1.x, bb1.y, bb1.z, bb1.w};
        #pragma unroll
        for (int i = 0; i < 4; ++i) {
            float4 h0, h1;
            h0.x = fmaxf(acc[i][0] + bb[0], 0.f);
            h0.y = fmaxf(acc[i][1] + bb[1], 0.f);
            h0.z = fmaxf(acc[i][2] + bb[2], 0.f);
            h0.w = fmaxf(acc[i][3] + bb[3], 0.f);
            h1.x = fmaxf(acc[i][4] + bb[4], 0.f);
            h1.y = fmaxf(acc[i][5] + bb[5], 0.f);
            h1.z = fmaxf(acc[i][6] + bb[6], 0.f);
            h1.w = fmaxf(acc[i][7] + bb[7], 0.f);
            *(float4*)(XAs + (4 * ty + i) * 132 + 8 * tx)     = h0;
            *(float4*)(XAs + (4 * ty + i) * 132 + 8 * tx + 4) = h1;
        }
    }
    #pragma unroll
    for (int i = 0; i < 8; ++i) {
        int c = t + i * 256;
        int row = c >> 4, col4 = (c & 15) << 2;
        float4 v = (col4 < 32) ? *(const float4*)(Wmu + row * 32 + col4)
                               : *(const float4*)(Wls + row * 32 + col4 - 32);
        *(float4*)(Ws + row * 64 + col4) = v;
    }
    __syncthreads();

    float a2c[4][4];
    #pragma unroll
    for (int i = 0; i < 4; ++i)
        #pragma unroll
        for (int j = 0; j < 4; ++j) a2c[i][j] = 0.f;
    #pragma unroll 4
    for (int k = 0; k < 128; ++k) {
        float h0 = XAs[(4 * ty + 0) * 132 + k];
        float h1 = XAs[(4 * ty + 1) * 132 + k];
        float h2 = XAs[(4 * ty + 2) * 132 + k];
        float h3 = XAs[(4 * ty + 3) * 132 + k];
        float4 wv = *(const float4*)(Ws + k * 64 + 4 * tx);
        float hv[4] = {h0, h1, h2, h3};
        float wa[4] = {wv.x, wv.y, wv.z, wv.w};
        #pragma unroll
        for (int i = 0; i < 4; ++i)
            #pragma unroll
            for (int j = 0; j < 4; ++j) a2c[i][j] += hv[i] * wa[j];
    }
    {
        float4 bv = (tx < 8) ? *(const float4*)(bmu + 4 * tx)
                             : *(const float4*)(bls + 4 * (tx - 8));
        float ba[4] = {bv.x, bv.y, bv.z, bv.w};
        #pragma unroll
        for (int i = 0; i < 4; ++i)
            #pragma unroll
            for (int j = 0; j < 4; ++j) a2c[i][j] += ba[j];
    }
    float oth[4][4];
    #pragma unroll
    for (int i = 0; i < 4; ++i)
        #pragma unroll
        for (int j = 0; j < 4; ++j) oth[i][j] = __shfl_xor(a2c[i][j], 8);

    float klsum = 0.f;
    {
        int i0 = (tx < 8) ? 0 : 2;
        int l0 = 4 * (tx & 7);
        #pragma unroll
        for (int ii = 0; ii < 2; ++ii) {
            int i = i0 + ii;
            int rowg = row0 + 4 * ty + i;
            float mu[4], lsv[4];
            #pragma unroll
            for (int j = 0; j < 4; ++j) {
                mu[j]  = (tx < 8) ? a2c[i][j] : oth[i][j];
                lsv[j] = (tx < 8) ? oth[i][j] : a2c[i][j];
            }
            float4 ev = *(const float4*)(eps + (size_t)rowg * 32 + l0);
            float ea[4] = {ev.x, ev.y, ev.z, ev.w};
            float4 zv;
            float zz[4];
            #pragma unroll
            for (int j = 0; j < 4; ++j) {
                float s = expf(lsv[j]);
                zz[j] = mu[j] + s * ea[j];
                klsum += s * s + mu[j] * mu[j] - 1.f - 2.f * lsv[j];
            }
            zv.x = zz[0]; zv.y = zz[1]; zv.z = zz[2]; zv.w = zz[3];
            *(float4*)(z + (size_t)rowg * 32 + l0) = zv;
        }
    }
    RED[t] = klsum;
    __syncthreads();
    for (int s = 128; s > 0; s >>= 1) {
        if (t < s) RED[t] += RED[t + s];
        __syncthreads();
    }
    if (t == 0) atomicAdd(&kls[g], 0.5f * RED[0]);
}

// ---------------------------------------------------------------------------
// Decoder: 2 blocks per graph (i-halves). 8x4 register tiles over the
// 64x128 logits slab; masked softplus; atomicAdd partial log_prob.
__global__ __launch_bounds__(256) void k_decoder(
    const float* __restrict__ z, const unsigned* __restrict__ bitmap,
    float* __restrict__ logp)
{
    __shared__ float zT[32 * 132];
    __shared__ unsigned bm[PW_];
    __shared__ float RED[256];
    int b = blockIdx.x >> 1, half = blockIdx.x & 1, t = threadIdx.x;

    #pragma unroll
    for (int i = 0; i < 16; ++i) {
        int c = t + i * 256;
        int n = c >> 5, l = c & 31;
        zT[l * 132 + n] = z[((size_t)b * N_ + n) * L_ + l];
    }
    if (t < PW_) bm[t] = bitmap[b * PW_ + t];
    __syncthreads();

    int i0 = half * 64 + ((t >> 5) << 3);   // 8 i-groups x 8 rows
    int j0 = (t & 31) << 2;                 // 32 j-groups x 4 cols
    float g[8][4];
    #pragma unroll
    for (int a = 0; a < 8; ++a)
        #pragma unroll
        for (int c = 0; c < 4; ++c) g[a][c] = 0.f;

    #pragma unroll 4
    for (int l = 0; l < 32; ++l) {
        float4 a0 = *(const float4*)(zT + l * 132 + i0);
        float4 a1 = *(const float4*)(zT + l * 132 + i0 + 4);
        float4 b0 = *(const float4*)(zT + l * 132 + j0);
        float za[8] = {a0.x, a0.y, a0.z, a0.w, a1.x, a1.y, a1.z, a1.w};
        float zb[4] = {b0.x, b0.y, b0.z, b0.w};
        #pragma unroll
        for (int a = 0; a < 8; ++a)
            #pragma unroll
            for (int c = 0; c < 4; ++c) g[a][c] += za[a] * zb[c];
    }

    float sum = 0.f;
    #pragma unroll
    for (int a = 0; a < 8; ++a) {
        int i = i0 + a;
        #pragma unroll
        for (int c = 0; c < 4; ++c) {
            int j = j0 + c;
            if (j > i) {
                float lg = g[a][c];
                int p = i * (255 - i) / 2 + (j - i - 1);
                unsigned bit = (bm[p >> 5] >> (p & 31)) & 1u;
                float sp = log1pf(expf(-fabsf(lg))) + fmaxf(lg, 0.f);
                sum += bit ? (lg - sp) : (-sp);
            }
        }
    }
    RED[t] = sum;
    __syncthreads();
    for (int s = 128; s > 0; s >>= 1) {
        if (t < s) RED[t] += RED[t + s];
        __syncthreads();
    }
    if (t == 0) atomicAdd(&logp[b], RED[0]);
}

// ---------------------------------------------------------------------------
__global__ __launch_bounds__(256) void k_finalize(
    const float* __restrict__ kls, const float* __restrict__ logp,
    float* __restrict__ out)
{
    __shared__ float RED[256];
    int t = threadIdx.x;
    RED[t] = logp[t] - kls[t];
    __syncthreads();
    for (int s = 128; s > 0; s >>= 1) {
        if (t < s) RED[t] += RED[t + s];
        __syncthreads();
    }
    if (t == 0) out[0] = -RED[0] * (1.0f / 256.0f);
}

// ---------------------------------------------------------------------------
extern "C" void kernel_launch(void* const* d_in, const int* in_sizes, int n_in,
                              void* d_out, int out_size, void* d_ws, size_t ws_size,
                              hipStream_t stream) {
    const float* x   = (const float*)d_in[0];
    const int*   ei  = (const int*)d_in[1];
    // d_in[2] = batch (unused; block-contiguous layout known)
    const float* eps = (const float*)d_in[3];
    const float* W1  = (const float*)d_in[4];
    const float* b1  = (const float*)d_in[5];
    const float* Wmu = (const float*)d_in[6];
    const float* bmu = (const float*)d_in[7];
    const float* Wls = (const float*)d_in[8];
    const float* bls = (const float*)d_in[9];

    unsigned* wsw = (unsigned*)d_ws;
    unsigned*      ndeg = wsw + NDEG_OFF;
    unsigned*      bm   = wsw + BM_OFF;
    float*         kls  = (float*)(wsw + KLS_OFF);
    float*         logp = (float*)(wsw + LP_OFF);
    unsigned char* adj  = (unsigned char*)(wsw + ADJ_OFF);
    float*         xa   = (float*)(wsw + XA_OFF);
    float*         z    = (float*)(wsw + Z_OFF);

    hipMemsetAsync(d_ws, 0, ZERO_WORDS * sizeof(unsigned), stream);

    k_build    <<<E_ / 256, 256, 0, stream>>>(ei, ndeg, adj, bm);
    k_aggregate<<<(B_ * N_) / 16, 256, 0, stream>>>(x, ndeg, adj, xa);
    k_encoder  <<<512, 256, 0, stream>>>(xa, W1, b1, Wmu, bmu, Wls, bls,
                                         eps, z, kls);
    k_decoder  <<<2 * B_, 256, 0, stream>>>(z, bm, logp);
    k_finalize <<<1, 256, 0, stream>>>(kls, logp, (float*)d_out);
}

// Round 5
// 209.382 us; speedup vs baseline: 4.9377x; 1.0134x over previous
//
#include <hip/hip_runtime.h>
#include <math.h>

#define B_ 256
#define N_ 128
#define D_ 128
#define L_ 32
#define E_ 262144
#define PW_ 254          // bitmap words per graph = 8128/32
#define DCAP 96          // per-node neighbor capacity (max deg ~70 expected)

// workspace layout (u32 units)
#define NDEG_OFF 0               // 32768 u32 per-node degree counters
#define BM_OFF   32768           // 65024 u32 pair-target bitmap
#define KLS_OFF  97792           // 256 f32 per-graph KL sums
#define LP_OFF   98048           // 256 f32 per-graph log_prob sums
#define ADJ_OFF  98304           // 32768*96 u8 CSR neighbor lists (786432 u32)
#define Z_OFF    884736          // 32768*32 f32 latents
#define ZERO_WORDS 98304         // ndeg + bitmap + kls + logp

// ---------------------------------------------------------------------------
// Per-edge: CSR adjacency build (atomics over 32768 node counters) + bitmap.
__global__ __launch_bounds__(256) void k_build(
    const int* __restrict__ ei, unsigned* __restrict__ ndeg,
    unsigned char* __restrict__ adj, unsigned* __restrict__ bm)
{
    int e = blockIdx.x * 256 + threadIdx.x;
    int src = ei[e], dst = ei[E_ + e];
    unsigned s1 = atomicAdd(&ndeg[src], 1u);
    if (s1 < DCAP) adj[(size_t)src * DCAP + s1] = (unsigned char)(dst & 127);
    unsigned s2 = atomicAdd(&ndeg[dst], 1u);
    if (s2 < DCAP) adj[(size_t)dst * DCAP + s2] = (unsigned char)(src & 127);
    int li = src & 127, lj = dst & 127, g = src >> 7;
    int p = li * (255 - li) / 2 + (lj - li - 1);
    atomicOr(&bm[g * PW_ + (p >> 5)], 1u << (p & 31));
}

// ---------------------------------------------------------------------------
// Fused gather+encoder: block = 64 rows (half a graph).
// Phase G: gather XA rows (x[n] + sum nbr x[m]) straight from global into LDS
//          (32 threads/node, 1 float4 each, 4-neighbor index prefetch).
// Phase 1: h = relu(XA @ W1 + b1), W1 staged in K-quarters (16 KB).
// Phase 2: [mu|ls] = h @ WB + bias, WB staged in K-halves (16 KB).
// Phase 3: z = mu + exp(ls)*eps, KL reduce -> atomicAdd kls[g].
// LDS ~50 KB -> 3 blocks/CU.
__global__ __launch_bounds__(256) void k_encoder(
    const float* __restrict__ x, const unsigned* __restrict__ ndeg,
    const unsigned char* __restrict__ adj,
    const float* __restrict__ W1, const float* __restrict__ b1,
    const float* __restrict__ Wmu, const float* __restrict__ bmu,
    const float* __restrict__ Wls, const float* __restrict__ bls,
    const float* __restrict__ eps,
    float* __restrict__ z, float* __restrict__ kls)
{
    __shared__ float XAs[64 * 132];   // 33792 B; later reused as HS
    __shared__ float Ws[4096];        // 16384 B; W1 k-quarter / WB k-half
    __shared__ float RED[256];
    int t = threadIdx.x;
    int row0 = blockIdx.x * 64;
    int g = blockIdx.x >> 1;
    int ty = t >> 4, tx = t & 15;

    // ---- phase G: gather 64 XA rows; 8 passes x 8 nodes, 32 threads/node ----
    {
        int nidx = t >> 5;                // node-within-pass 0..7
        int fo = (t & 31) << 2;           // float offset 0..124
        #pragma unroll 2
        for (int p = 0; p < 8; ++p) {
            int lrow = p * 8 + nidx;      // block-local row 0..63
            int gnode = row0 + lrow;
            const float* xr = x + (size_t)gnode * 128 + fo;
            float4 acc = *(const float4*)xr;
            int deg = (int)ndeg[gnode];
            if (deg > DCAP) deg = DCAP;
            const unsigned char* al = adj + (size_t)gnode * DCAP;
            const float* gx = x + (size_t)(gnode & ~127) * 128 + fo;
            int e = 0;
            for (; e + 4 <= deg; e += 4) {
                unsigned pk = *(const unsigned*)(al + e);
                float4 v0 = *(const float4*)(gx + (pk & 255u) * 128);
                float4 v1 = *(const float4*)(gx + ((pk >> 8) & 255u) * 128);
                float4 v2 = *(const float4*)(gx + ((pk >> 16) & 255u) * 128);
                float4 v3 = *(const float4*)(gx + (pk >> 24) * 128);
                acc.x += v0.x + v1.x + v2.x + v3.x;
                acc.y += v0.y + v1.y + v2.y + v3.y;
                acc.z += v0.z + v1.z + v2.z + v3.z;
                acc.w += v0.w + v1.w + v2.w + v3.w;
            }
            for (; e < deg; ++e) {
                float4 v = *(const float4*)(gx + (unsigned)al[e] * 128);
                acc.x += v.x; acc.y += v.y; acc.z += v.z; acc.w += v.w;
            }
            *(float4*)(XAs + lrow * 132 + fo) = acc;
        }
    }
    __syncthreads();

    // ---- phase 1: GEMM1 in 4 K-quarters ----
    float acc[4][8];
    #pragma unroll
    for (int i = 0; i < 4; ++i)
        #pragma unroll
        for (int j = 0; j < 8; ++j) acc[i][j] = 0.f;

    for (int kq = 0; kq < 4; ++kq) {
        if (kq) __syncthreads();          // prior Ws reads done
        #pragma unroll
        for (int i = 0; i < 4; ++i) {
            int c = t + i * 256;          // 1024 float4 = 32x128 W1 rows
            ((float4*)Ws)[c] = ((const float4*)(W1 + kq * 4096))[c];
        }
        __syncthreads();
        #pragma unroll 4
        for (int k = 0; k < 32; ++k) {
            int kk = kq * 32 + k;
            float a0 = XAs[(4 * ty + 0) * 132 + kk];
            float a1 = XAs[(4 * ty + 1) * 132 + kk];
            float a2 = XAs[(4 * ty + 2) * 132 + kk];
            float a3 = XAs[(4 * ty + 3) * 132 + kk];
            float4 w0 = *(const float4*)(Ws + k * 128 + 8 * tx);
            float4 w1 = *(const float4*)(Ws + k * 128 + 8 * tx + 4);
            float av[4] = {a0, a1, a2, a3};
            float wv[8] = {w0.x, w0.y, w0.z, w0.w, w1.x, w1.y, w1.z, w1.w};
            #pragma unroll
            for (int i = 0; i < 4; ++i)
                #pragma unroll
                for (int j = 0; j < 8; ++j) acc[i][j] += av[i] * wv[j];
        }
    }
    __syncthreads();                      // all XAs/Ws reads done

    // ---- relu + b1 -> HS (XAs region) ----
    {
        float4 bb0 = *(const float4*)(b1 + 8 * tx);
        float4 bb1 = *(const float4*)(b1 + 8 * tx + 4);
        float bb[8] = {bb0.x, bb0.y, bb0.z, bb0.w, bb1.x, bb1.y, bb1.z, bb1.w};
        #pragma unroll
        for (int i = 0; i < 4; ++i) {
            float4 h0, h1;
            h0.x = fmaxf(acc[i][0] + bb[0], 0.f);
            h0.y = fmaxf(acc[i][1] + bb[1], 0.f);
            h0.z = fmaxf(acc[i][2] + bb[2], 0.f);
            h0.w = fmaxf(acc[i][3] + bb[3], 0.f);
            h1.x = fmaxf(acc[i][4] + bb[4], 0.f);
            h1.y = fmaxf(acc[i][5] + bb[5], 0.f);
            h1.z = fmaxf(acc[i][6] + bb[6], 0.f);
            h1.w = fmaxf(acc[i][7] + bb[7], 0.f);
            *(float4*)(XAs + (4 * ty + i) * 132 + 8 * tx)     = h0;
            *(float4*)(XAs + (4 * ty + i) * 132 + 8 * tx + 4) = h1;
        }
    }

    // ---- phase 2: GEMM2 in 2 K-halves; WB half = [Wmu|Wls] rows ----
    float a2c[4][4];
    #pragma unroll
    for (int i = 0; i < 4; ++i)
        #pragma unroll
        for (int j = 0; j < 4; ++j) a2c[i][j] = 0.f;

    for (int kh = 0; kh < 2; ++kh) {
        __syncthreads();                  // H visible (kh=0) / prior WB reads done
        #pragma unroll
        for (int i = 0; i < 4; ++i) {
            int c = t + i * 256;          // 1024 float4 = 64 rows x 64 cols
            int row = (c >> 4) + kh * 64, col4 = (c & 15) << 2;
            float4 v = (col4 < 32) ? *(const float4*)(Wmu + row * 32 + col4)
                                   : *(const float4*)(Wls + row * 32 + col4 - 32);
            *(float4*)(Ws + (c >> 4) * 64 + col4) = v;
        }
        __syncthreads();
        #pragma unroll 4
        for (int k = 0; k < 64; ++k) {
            int kk = kh * 64 + k;
            float h0 = XAs[(4 * ty + 0) * 132 + kk];
            float h1 = XAs[(4 * ty + 1) * 132 + kk];
            float h2 = XAs[(4 * ty + 2) * 132 + kk];
            float h3 = XAs[(4 * ty + 3) * 132 + kk];
            float4 wv = *(const float4*)(Ws + k * 64 + 4 * tx);
            float hv[4] = {h0, h1, h2, h3};
            float wa[4] = {wv.x, wv.y, wv.z, wv.w};
            #pragma unroll
            for (int i = 0; i < 4; ++i)
                #pragma unroll
                for (int j = 0; j < 4; ++j) a2c[i][j] += hv[i] * wa[j];
        }
    }
    {
        float4 bv = (tx < 8) ? *(const float4*)(bmu + 4 * tx)
                             : *(const float4*)(bls + 4 * (tx - 8));
        float ba[4] = {bv.x, bv.y, bv.z, bv.w};
        #pragma unroll
        for (int i = 0; i < 4; ++i)
            #pragma unroll
            for (int j = 0; j < 4; ++j) a2c[i][j] += ba[j];
    }
    // exchange mu<->ls with partner lane (tx ^ 8)
    float oth[4][4];
    #pragma unroll
    for (int i = 0; i < 4; ++i)
        #pragma unroll
        for (int j = 0; j < 4; ++j) oth[i][j] = __shfl_xor(a2c[i][j], 8);

    // ---- phase 3: z, KL ----
    float klsum = 0.f;
    {
        int i0 = (tx < 8) ? 0 : 2;
        int l0 = 4 * (tx & 7);
        #pragma unroll
        for (int ii = 0; ii < 2; ++ii) {
            int i = i0 + ii;
            int rowg = row0 + 4 * ty + i;
            float mu[4], lsv[4];
            #pragma unroll
            for (int j = 0; j < 4; ++j) {
                mu[j]  = (tx < 8) ? a2c[i][j] : oth[i][j];
                lsv[j] = (tx < 8) ? oth[i][j] : a2c[i][j];
            }
            float4 ev = *(const float4*)(eps + (size_t)rowg * 32 + l0);
            float ea[4] = {ev.x, ev.y, ev.z, ev.w};
            float4 zv;
            float zz[4];
            #pragma unroll
            for (int j = 0; j < 4; ++j) {
                float s = expf(lsv[j]);
                zz[j] = mu[j] + s * ea[j];
                klsum += s * s + mu[j] * mu[j] - 1.f - 2.f * lsv[j];
            }
            zv.x = zz[0]; zv.y = zz[1]; zv.z = zz[2]; zv.w = zz[3];
            *(float4*)(z + (size_t)rowg * 32 + l0) = zv;
        }
    }
    RED[t] = klsum;
    __syncthreads();
    for (int s = 128; s > 0; s >>= 1) {
        if (t < s) RED[t] += RED[t + s];
        __syncthreads();
    }
    if (t == 0) atomicAdd(&kls[g], 0.5f * RED[0]);
}

// ---------------------------------------------------------------------------
// Decoder: 2 blocks per graph (i-halves). 8x4 register tiles over the
// 64x128 logits slab; masked softplus; atomicAdd partial log_prob.
__global__ __launch_bounds__(256) void k_decoder(
    const float* __restrict__ z, const unsigned* __restrict__ bitmap,
    float* __restrict__ logp)
{
    __shared__ float zT[32 * 132];
    __shared__ unsigned bm[PW_];
    __shared__ float RED[256];
    int b = blockIdx.x >> 1, half = blockIdx.x & 1, t = threadIdx.x;

    #pragma unroll
    for (int i = 0; i < 16; ++i) {
        int c = t + i * 256;
        int n = c >> 5, l = c & 31;
        zT[l * 132 + n] = z[((size_t)b * N_ + n) * L_ + l];
    }
    if (t < PW_) bm[t] = bitmap[b * PW_ + t];
    __syncthreads();

    int i0 = half * 64 + ((t >> 5) << 3);   // 8 i-groups x 8 rows
    int j0 = (t & 31) << 2;                 // 32 j-groups x 4 cols
    float g[8][4];
    #pragma unroll
    for (int a = 0; a < 8; ++a)
        #pragma unroll
        for (int c = 0; c < 4; ++c) g[a][c] = 0.f;

    #pragma unroll 4
    for (int l = 0; l < 32; ++l) {
        float4 a0 = *(const float4*)(zT + l * 132 + i0);
        float4 a1 = *(const float4*)(zT + l * 132 + i0 + 4);
        float4 b0 = *(const float4*)(zT + l * 132 + j0);
        float za[8] = {a0.x, a0.y, a0.z, a0.w, a1.x, a1.y, a1.z, a1.w};
        float zb[4] = {b0.x, b0.y, b0.z, b0.w};
        #pragma unroll
        for (int a = 0; a < 8; ++a)
            #pragma unroll
            for (int c = 0; c < 4; ++c) g[a][c] += za[a] * zb[c];
    }

    float sum = 0.f;
    #pragma unroll
    for (int a = 0; a < 8; ++a) {
        int i = i0 + a;
        #pragma unroll
        for (int c = 0; c < 4; ++c) {
            int j = j0 + c;
            if (j > i) {
                float lg = g[a][c];
                int p = i * (255 - i) / 2 + (j - i - 1);
                unsigned bit = (bm[p >> 5] >> (p & 31)) & 1u;
                float sp = log1pf(expf(-fabsf(lg))) + fmaxf(lg, 0.f);
                sum += bit ? (lg - sp) : (-sp);
            }
        }
    }
    RED[t] = sum;
    __syncthreads();
    for (int s = 128; s > 0; s >>= 1) {
        if (t < s) RED[t] += RED[t + s];
        __syncthreads();
    }
    if (t == 0) atomicAdd(&logp[b], RED[0]);
}

// ---------------------------------------------------------------------------
__global__ __launch_bounds__(256) void k_finalize(
    const float* __restrict__ kls, const float* __restrict__ logp,
    float* __restrict__ out)
{
    __shared__ float RED[256];
    int t = threadIdx.x;
    RED[t] = logp[t] - kls[t];
    __syncthreads();
    for (int s = 128; s > 0; s >>= 1) {
        if (t < s) RED[t] += RED[t + s];
        __syncthreads();
    }
    if (t == 0) out[0] = -RED[0] * (1.0f / 256.0f);
}

// ---------------------------------------------------------------------------
extern "C" void kernel_launch(void* const* d_in, const int* in_sizes, int n_in,
                              void* d_out, int out_size, void* d_ws, size_t ws_size,
                              hipStream_t stream) {
    const float* x   = (const float*)d_in[0];
    const int*   ei  = (const int*)d_in[1];
    // d_in[2] = batch (unused; block-contiguous layout known)
    const float* eps = (const float*)d_in[3];
    const float* W1  = (const float*)d_in[4];
    const float* b1  = (const float*)d_in[5];
    const float* Wmu = (const float*)d_in[6];
    const float* bmu = (const float*)d_in[7];
    const float* Wls = (const float*)d_in[8];
    const float* bls = (const float*)d_in[9];

    unsigned* wsw = (unsigned*)d_ws;
    unsigned*      ndeg = wsw + NDEG_OFF;
    unsigned*      bm   = wsw + BM_OFF;
    float*         kls  = (float*)(wsw + KLS_OFF);
    float*         logp = (float*)(wsw + LP_OFF);
    unsigned char* adj  = (unsigned char*)(wsw + ADJ_OFF);
    float*         z    = (float*)(wsw + Z_OFF);

    hipMemsetAsync(d_ws, 0, ZERO_WORDS * sizeof(unsigned), stream);

    k_build   <<<E_ / 256, 256, 0, stream>>>(ei, ndeg, adj, bm);
    k_encoder <<<512, 256, 0, stream>>>(x, ndeg, adj, W1, b1, Wmu, bmu,
                                        Wls, bls, eps, z, kls);
    k_decoder <<<2 * B_, 256, 0, stream>>>(z, bm, logp);
    k_finalize<<<1, 256, 0, stream>>>(kls, logp, (float*)d_out);
}

// Round 6
// 201.069 us; speedup vs baseline: 5.1418x; 1.0413x over previous
//
#include <hip/hip_runtime.h>
#include <math.h>

#define B_ 256
#define N_ 128
#define D_ 128
#define L_ 32
#define E_ 262144
#define PW_ 254          // bitmap words per graph = 8128/32
#define DCAP 96          // per-node neighbor capacity (max deg ~70 expected)

// workspace layout (u32 units)
#define NDEG_OFF 0               // 32768 u32 per-node degree counters
#define BM_OFF   32768           // 65024 u32 pair-target bitmap
#define KLS_OFF  97792           // 256 f32 per-graph KL sums
#define LP_OFF   98048           // 256 f32 per-graph log_prob sums
#define ADJ_OFF  98304           // 32768*96 u8 CSR neighbor lists (786432 u32)
#define Z_OFF    884736          // 32768*32 f32 latents
#define ZERO_WORDS 98304         // ndeg + bitmap + kls + logp

// ---------------------------------------------------------------------------
// Per-edge: CSR adjacency build (atomics over 32768 node counters) + bitmap.
__global__ __launch_bounds__(256) void k_build(
    const int* __restrict__ ei, unsigned* __restrict__ ndeg,
    unsigned char* __restrict__ adj, unsigned* __restrict__ bm)
{
    int e = blockIdx.x * 256 + threadIdx.x;
    int src = ei[e], dst = ei[E_ + e];
    unsigned s1 = atomicAdd(&ndeg[src], 1u);
    if (s1 < DCAP) adj[(size_t)src * DCAP + s1] = (unsigned char)(dst & 127);
    unsigned s2 = atomicAdd(&ndeg[dst], 1u);
    if (s2 < DCAP) adj[(size_t)dst * DCAP + s2] = (unsigned char)(src & 127);
    int li = src & 127, lj = dst & 127, g = src >> 7;
    int p = li * (255 - li) / 2 + (lj - li - 1);
    atomicOr(&bm[g * PW_ + (p >> 5)], 1u << (p & 31));
}

// ---------------------------------------------------------------------------
// Fused gather+encoder: block = 32 rows (quarter graph), 1024 blocks,
// ~34 KB LDS -> 4 blocks/CU (16 waves/CU).
// Micro-tile: rg = t>>5 (4 rows at 4*rg), cg = t&31 (4 cols at 4*cg) —
// B-operand float4 reads span all 32 banks; A-operand float4 over k.
__global__ __launch_bounds__(256, 4) void k_encoder(
    const float* __restrict__ x, const unsigned* __restrict__ ndeg,
    const unsigned char* __restrict__ adj,
    const float* __restrict__ W1, const float* __restrict__ b1,
    const float* __restrict__ Wmu, const float* __restrict__ bmu,
    const float* __restrict__ Wls, const float* __restrict__ bls,
    const float* __restrict__ eps,
    float* __restrict__ z, float* __restrict__ kls)
{
    __shared__ float XAs[32 * 132];   // 16896 B; reused as HS after GEMM1
    __shared__ float Ws[4096];        // 16384 B; W1 k-quarter / WB k-half
    __shared__ float RED[256];
    int t = threadIdx.x;
    int row0 = blockIdx.x * 32;
    int g = blockIdx.x >> 2;
    int rg = t >> 5;                  // 0..7
    int cg = t & 31;                  // 0..31

    // ---- phase G: gather 32 XA rows; 2 passes x 16 nodes, 16 thr/node ----
    {
        int nidx = t >> 4;            // 0..15
        int fo = (t & 15) * 8;        // float offset 0..120
        for (int p = 0; p < 2; ++p) {
            int lrow = p * 16 + nidx;
            int gnode = row0 + lrow;
            const float* xr = x + (size_t)gnode * 128 + fo;
            float4 a0 = *(const float4*)xr;
            float4 a1 = *(const float4*)(xr + 4);
            int deg = (int)ndeg[gnode];
            if (deg > DCAP) deg = DCAP;
            const unsigned char* al = adj + (size_t)gnode * DCAP;
            const float* gx = x + (size_t)(gnode & ~127) * 128 + fo;
            int e = 0;
            for (; e + 4 <= deg; e += 4) {
                unsigned pk = *(const unsigned*)(al + e);
                const float* r0 = gx + (pk & 255u) * 128;
                const float* r1 = gx + ((pk >> 8) & 255u) * 128;
                const float* r2 = gx + ((pk >> 16) & 255u) * 128;
                const float* r3 = gx + (pk >> 24) * 128;
                float4 v00 = *(const float4*)r0, v01 = *(const float4*)(r0 + 4);
                float4 v10 = *(const float4*)r1, v11 = *(const float4*)(r1 + 4);
                float4 v20 = *(const float4*)r2, v21 = *(const float4*)(r2 + 4);
                float4 v30 = *(const float4*)r3, v31 = *(const float4*)(r3 + 4);
                a0.x += v00.x + v10.x + v20.x + v30.x;
                a0.y += v00.y + v10.y + v20.y + v30.y;
                a0.z += v00.z + v10.z + v20.z + v30.z;
                a0.w += v00.w + v10.w + v20.w + v30.w;
                a1.x += v01.x + v11.x + v21.x + v31.x;
                a1.y += v01.y + v11.y + v21.y + v31.y;
                a1.z += v01.z + v11.z + v21.z + v31.z;
                a1.w += v01.w + v11.w + v21.w + v31.w;
            }
            for (; e < deg; ++e) {
                const float* r = gx + (unsigned)al[e] * 128;
                float4 v0 = *(const float4*)r, v1 = *(const float4*)(r + 4);
                a0.x += v0.x; a0.y += v0.y; a0.z += v0.z; a0.w += v0.w;
                a1.x += v1.x; a1.y += v1.y; a1.z += v1.z; a1.w += v1.w;
            }
            *(float4*)(XAs + lrow * 132 + fo) = a0;
            *(float4*)(XAs + lrow * 132 + fo + 4) = a1;
        }
    }
    __syncthreads();

    // ---- phase 1: h = relu(XA @ W1 + b1), W1 in 4 K-quarters ----
    float acc[4][4];
    #pragma unroll
    for (int i = 0; i < 4; ++i)
        #pragma unroll
        for (int j = 0; j < 4; ++j) acc[i][j] = 0.f;

    for (int kq = 0; kq < 4; ++kq) {
        if (kq) __syncthreads();
        #pragma unroll
        for (int i = 0; i < 4; ++i) {
            int c = t + i * 256;      // 1024 float4 = 32x128 W1 rows
            ((float4*)Ws)[c] = ((const float4*)(W1 + kq * 4096))[c];
        }
        __syncthreads();
        #pragma unroll 2
        for (int k = 0; k < 32; k += 4) {
            float4 av[4], wv[4];
            #pragma unroll
            for (int i = 0; i < 4; ++i)
                av[i] = *(const float4*)(XAs + (4 * rg + i) * 132 + kq * 32 + k);
            #pragma unroll
            for (int dk = 0; dk < 4; ++dk)
                wv[dk] = *(const float4*)(Ws + (k + dk) * 128 + 4 * cg);
            #pragma unroll
            for (int i = 0; i < 4; ++i) {
                acc[i][0] += av[i].x * wv[0].x + av[i].y * wv[1].x + av[i].z * wv[2].x + av[i].w * wv[3].x;
                acc[i][1] += av[i].x * wv[0].y + av[i].y * wv[1].y + av[i].z * wv[2].y + av[i].w * wv[3].y;
                acc[i][2] += av[i].x * wv[0].z + av[i].y * wv[1].z + av[i].z * wv[2].z + av[i].w * wv[3].z;
                acc[i][3] += av[i].x * wv[0].w + av[i].y * wv[1].w + av[i].z * wv[2].w + av[i].w * wv[3].w;
            }
        }
    }
    __syncthreads();                  // all XAs reads done -> reuse as HS

    {
        float4 bb = *(const float4*)(b1 + 4 * cg);
        #pragma unroll
        for (int i = 0; i < 4; ++i) {
            float4 h;
            h.x = fmaxf(acc[i][0] + bb.x, 0.f);
            h.y = fmaxf(acc[i][1] + bb.y, 0.f);
            h.z = fmaxf(acc[i][2] + bb.z, 0.f);
            h.w = fmaxf(acc[i][3] + bb.w, 0.f);
            *(float4*)(XAs + (4 * rg + i) * 132 + 4 * cg) = h;
        }
    }

    // ---- phase 2: [mu|ls] = h @ WB + bias, WB in 2 K-halves ----
    float a3[4][2];
    #pragma unroll
    for (int i = 0; i < 4; ++i) { a3[i][0] = 0.f; a3[i][1] = 0.f; }

    for (int kh = 0; kh < 2; ++kh) {
        __syncthreads();              // HS visible (kh=0) / prior Ws reads done
        #pragma unroll
        for (int i = 0; i < 4; ++i) {
            int c = t + i * 256;      // 1024 float4 = 64 rows x 64 cols
            int row = c >> 4, col4 = (c & 15) << 2;
            int rowg = kh * 64 + row;
            float4 v = (col4 < 32) ? *(const float4*)(Wmu + rowg * 32 + col4)
                                   : *(const float4*)(Wls + rowg * 32 + col4 - 32);
            *(float4*)(Ws + row * 64 + col4) = v;
        }
        __syncthreads();
        #pragma unroll 2
        for (int k = 0; k < 64; k += 4) {
            float4 av[4];
            float2 wv[4];
            #pragma unroll
            for (int i = 0; i < 4; ++i)
                av[i] = *(const float4*)(XAs + (4 * rg + i) * 132 + kh * 64 + k);
            #pragma unroll
            for (int dk = 0; dk < 4; ++dk)
                wv[dk] = *(const float2*)(Ws + (k + dk) * 64 + 2 * cg);
            #pragma unroll
            for (int i = 0; i < 4; ++i) {
                a3[i][0] += av[i].x * wv[0].x + av[i].y * wv[1].x + av[i].z * wv[2].x + av[i].w * wv[3].x;
                a3[i][1] += av[i].x * wv[0].y + av[i].y * wv[1].y + av[i].z * wv[2].y + av[i].w * wv[3].y;
            }
        }
    }
    {
        float2 bv = (cg < 16) ? *(const float2*)(bmu + 2 * cg)
                              : *(const float2*)(bls + 2 * cg - 32);
        #pragma unroll
        for (int i = 0; i < 4; ++i) { a3[i][0] += bv.x; a3[i][1] += bv.y; }
    }

    // exchange mu<->ls with partner lane (cg ^ 16)
    float o3[4][2];
    #pragma unroll
    for (int i = 0; i < 4; ++i) {
        o3[i][0] = __shfl_xor(a3[i][0], 16);
        o3[i][1] = __shfl_xor(a3[i][1], 16);
    }

    // ---- phase 3: z = mu + exp(ls)*eps, KL ----
    float klsum = 0.f;
    if (cg < 16) {                    // this lane holds mu; partner held ls
        int lo = cg;
        #pragma unroll
        for (int i = 0; i < 4; ++i) {
            int rowg = row0 + 4 * rg + i;
            float mu0 = a3[i][0], mu1 = a3[i][1];
            float ls0 = o3[i][0], ls1 = o3[i][1];
            float2 ev = *(const float2*)(eps + (size_t)rowg * 32 + 2 * lo);
            float s0 = expf(ls0), s1 = expf(ls1);
            float2 zv = make_float2(mu0 + s0 * ev.x, mu1 + s1 * ev.y);
            *(float2*)(z + (size_t)rowg * 32 + 2 * lo) = zv;
            klsum += s0 * s0 + mu0 * mu0 - 1.f - 2.f * ls0
                   + s1 * s1 + mu1 * mu1 - 1.f - 2.f * ls1;
        }
    }
    RED[t] = klsum;
    __syncthreads();
    for (int s = 128; s > 0; s >>= 1) {
        if (t < s) RED[t] += RED[t + s];
        __syncthreads();
    }
    if (t == 0) atomicAdd(&kls[g], 0.5f * RED[0]);
}

// ---------------------------------------------------------------------------
// Decoder: 4 blocks per graph (i-quarters). 4x4 register tiles over the
// 32x128 logits slab; masked softplus; atomicAdd partial log_prob.
__global__ __launch_bounds__(256) void k_decoder(
    const float* __restrict__ z, const unsigned* __restrict__ bitmap,
    float* __restrict__ logp)
{
    __shared__ float zT[32 * 132];
    __shared__ unsigned bm[PW_];
    __shared__ float RED[256];
    int b = blockIdx.x >> 2, quar = blockIdx.x & 3, t = threadIdx.x;

    #pragma unroll
    for (int i = 0; i < 16; ++i) {
        int c = t + i * 256;
        int n = c >> 5, l = c & 31;
        zT[l * 132 + n] = z[((size_t)b * N_ + n) * L_ + l];
    }
    if (t < PW_) bm[t] = bitmap[b * PW_ + t];
    __syncthreads();

    int i0 = quar * 32 + ((t >> 5) << 2);   // 8 i-groups x 4 rows
    int j0 = (t & 31) << 2;                 // 32 j-groups x 4 cols
    float g[4][4];
    #pragma unroll
    for (int a = 0; a < 4; ++a)
        #pragma unroll
        for (int c = 0; c < 4; ++c) g[a][c] = 0.f;

    #pragma unroll 4
    for (int l = 0; l < 32; ++l) {
        float4 a0 = *(const float4*)(zT + l * 132 + i0);
        float4 b0 = *(const float4*)(zT + l * 132 + j0);
        float za[4] = {a0.x, a0.y, a0.z, a0.w};
        float zb[4] = {b0.x, b0.y, b0.z, b0.w};
        #pragma unroll
        for (int a = 0; a < 4; ++a)
            #pragma unroll
            for (int c = 0; c < 4; ++c) g[a][c] += za[a] * zb[c];
    }

    float sum = 0.f;
    #pragma unroll
    for (int a = 0; a < 4; ++a) {
        int i = i0 + a;
        #pragma unroll
        for (int c = 0; c < 4; ++c) {
            int j = j0 + c;
            if (j > i) {
                float lg = g[a][c];
                int p = i * (255 - i) / 2 + (j - i - 1);
                unsigned bit = (bm[p >> 5] >> (p & 31)) & 1u;
                float sp = log1pf(expf(-fabsf(lg))) + fmaxf(lg, 0.f);
                sum += bit ? (lg - sp) : (-sp);
            }
        }
    }
    RED[t] = sum;
    __syncthreads();
    for (int s = 128; s > 0; s >>= 1) {
        if (t < s) RED[t] += RED[t + s];
        __syncthreads();
    }
    if (t == 0) atomicAdd(&logp[b], RED[0]);
}

// ---------------------------------------------------------------------------
__global__ __launch_bounds__(256) void k_finalize(
    const float* __restrict__ kls, const float* __restrict__ logp,
    float* __restrict__ out)
{
    __shared__ float RED[256];
    int t = threadIdx.x;
    RED[t] = logp[t] - kls[t];
    __syncthreads();
    for (int s = 128; s > 0; s >>= 1) {
        if (t < s) RED[t] += RED[t + s];
        __syncthreads();
    }
    if (t == 0) out[0] = -RED[0] * (1.0f / 256.0f);
}

// ---------------------------------------------------------------------------
extern "C" void kernel_launch(void* const* d_in, const int* in_sizes, int n_in,
                              void* d_out, int out_size, void* d_ws, size_t ws_size,
                              hipStream_t stream) {
    const float* x   = (const float*)d_in[0];
    const int*   ei  = (const int*)d_in[1];
    // d_in[2] = batch (unused; block-contiguous layout known)
    const float* eps = (const float*)d_in[3];
    const float* W1  = (const float*)d_in[4];
    const float* b1  = (const float*)d_in[5];
    const float* Wmu = (const float*)d_in[6];
    const float* bmu = (const float*)d_in[7];
    const float* Wls = (const float*)d_in[8];
    const float* bls = (const float*)d_in[9];

    unsigned* wsw = (unsigned*)d_ws;
    unsigned*      ndeg = wsw + NDEG_OFF;
    unsigned*      bm   = wsw + BM_OFF;
    float*         kls  = (float*)(wsw + KLS_OFF);
    float*         logp = (float*)(wsw + LP_OFF);
    unsigned char* adj  = (unsigned char*)(wsw + ADJ_OFF);
    float*         z    = (float*)(wsw + Z_OFF);

    hipMemsetAsync(d_ws, 0, ZERO_WORDS * sizeof(unsigned), stream);

    k_build   <<<E_ / 256, 256, 0, stream>>>(ei, ndeg, adj, bm);
    k_encoder <<<1024, 256, 0, stream>>>(x, ndeg, adj, W1, b1, Wmu, bmu,
                                         Wls, bls, eps, z, kls);
    k_decoder <<<4 * B_, 256, 0, stream>>>(z, bm, logp);
    k_finalize<<<1, 256, 0, stream>>>(kls, logp, (float*)d_out);
}

// Round 7
// 188.474 us; speedup vs baseline: 5.4854x; 1.0668x over previous
//
#include <hip/hip_runtime.h>
#include <math.h>

#define B_ 256
#define N_ 128
#define D_ 128
#define L_ 32
#define E_ 262144
#define PW_ 254          // bitmap words per graph = 8128/32
#define DCAP 96          // per-node neighbor capacity (max deg ~70 expected)

// workspace layout (u32 units)
#define NDEG_OFF 0               // 32768 u32 per-node degree counters
#define BM_OFF   32768           // 65024 u32 pair-target bitmap
#define KLS_OFF  97792           // 256 f32 per-graph KL sums
#define LP_OFF   98048           // 256 f32 per-graph log_prob sums
#define ADJ_OFF  98304           // 32768*96 u8 CSR neighbor lists (786432 u32)
#define Z_OFF    884736          // 32768*32 f32 latents
#define ZERO_WORDS 98304         // ndeg + bitmap + kls + logp

// ---------------------------------------------------------------------------
// Per-edge: CSR adjacency build (atomics over 32768 node counters) + bitmap.
__global__ __launch_bounds__(256) void k_build(
    const int* __restrict__ ei, unsigned* __restrict__ ndeg,
    unsigned char* __restrict__ adj, unsigned* __restrict__ bm)
{
    int e = blockIdx.x * 256 + threadIdx.x;
    int src = ei[e], dst = ei[E_ + e];
    unsigned s1 = atomicAdd(&ndeg[src], 1u);
    if (s1 < DCAP) adj[(size_t)src * DCAP + s1] = (unsigned char)(dst & 127);
    unsigned s2 = atomicAdd(&ndeg[dst], 1u);
    if (s2 < DCAP) adj[(size_t)dst * DCAP + s2] = (unsigned char)(src & 127);
    int li = src & 127, lj = dst & 127, g = src >> 7;
    int p = li * (255 - li) / 2 + (lj - li - 1);
    atomicOr(&bm[g * PW_ + (p >> 5)], 1u << (p & 31));
}

// ---------------------------------------------------------------------------
// Fused gather+encoder: block = 32 rows (quarter graph), 1024 blocks.
// XCD swizzle: graph = blockIdx&255, quarter = blockIdx>>8 — 256≡0 (mod 8)
// puts all 4 quarters of a graph on ONE XCD so its 64 KB x-slab is HBM-
// fetched once and L2-served after. ~34 KB LDS -> 4 blocks/CU.
__global__ __launch_bounds__(256, 4) void k_encoder(
    const float* __restrict__ x, const unsigned* __restrict__ ndeg,
    const unsigned char* __restrict__ adj,
    const float* __restrict__ W1, const float* __restrict__ b1,
    const float* __restrict__ Wmu, const float* __restrict__ bmu,
    const float* __restrict__ Wls, const float* __restrict__ bls,
    const float* __restrict__ eps,
    float* __restrict__ z, float* __restrict__ kls)
{
    __shared__ float XAs[32 * 132];   // 16896 B; reused as HS after GEMM1
    __shared__ float Ws[4096];        // 16384 B; W1 k-quarter / WB k-half
    __shared__ float RED[256];
    int t = threadIdx.x;
    int g = blockIdx.x & 255;         // graph (fixes XCD: g % 8)
    int quar = blockIdx.x >> 8;       // 0..3
    int row0 = g * 128 + quar * 32;
    int rg = t >> 5;                  // 0..7
    int cg = t & 31;                  // 0..31

    // ---- phase G: gather 32 XA rows; 2 passes x 16 nodes, 16 thr/node ----
    {
        int nidx = t >> 4;            // 0..15
        int fo = (t & 15) * 8;        // float offset 0..120
        for (int p = 0; p < 2; ++p) {
            int lrow = p * 16 + nidx;
            int gnode = row0 + lrow;
            const float* xr = x + (size_t)gnode * 128 + fo;
            float4 a0 = *(const float4*)xr;
            float4 a1 = *(const float4*)(xr + 4);
            int deg = (int)ndeg[gnode];
            if (deg > DCAP) deg = DCAP;
            const unsigned char* al = adj + (size_t)gnode * DCAP;
            const float* gx = x + (size_t)(gnode & ~127) * 128 + fo;
            int e = 0;
            for (; e + 4 <= deg; e += 4) {
                unsigned pk = *(const unsigned*)(al + e);
                const float* r0 = gx + (pk & 255u) * 128;
                const float* r1 = gx + ((pk >> 8) & 255u) * 128;
                const float* r2 = gx + ((pk >> 16) & 255u) * 128;
                const float* r3 = gx + (pk >> 24) * 128;
                float4 v00 = *(const float4*)r0, v01 = *(const float4*)(r0 + 4);
                float4 v10 = *(const float4*)r1, v11 = *(const float4*)(r1 + 4);
                float4 v20 = *(const float4*)r2, v21 = *(const float4*)(r2 + 4);
                float4 v30 = *(const float4*)r3, v31 = *(const float4*)(r3 + 4);
                a0.x += v00.x + v10.x + v20.x + v30.x;
                a0.y += v00.y + v10.y + v20.y + v30.y;
                a0.z += v00.z + v10.z + v20.z + v30.z;
                a0.w += v00.w + v10.w + v20.w + v30.w;
                a1.x += v01.x + v11.x + v21.x + v31.x;
                a1.y += v01.y + v11.y + v21.y + v31.y;
                a1.z += v01.z + v11.z + v21.z + v31.z;
                a1.w += v01.w + v11.w + v21.w + v31.w;
            }
            for (; e < deg; ++e) {
                const float* r = gx + (unsigned)al[e] * 128;
                float4 v0 = *(const float4*)r, v1 = *(const float4*)(r + 4);
                a0.x += v0.x; a0.y += v0.y; a0.z += v0.z; a0.w += v0.w;
                a1.x += v1.x; a1.y += v1.y; a1.z += v1.z; a1.w += v1.w;
            }
            *(float4*)(XAs + lrow * 132 + fo) = a0;
            *(float4*)(XAs + lrow * 132 + fo + 4) = a1;
        }
    }
    __syncthreads();

    // ---- phase 1: h = relu(XA @ W1 + b1), W1 in 4 K-quarters ----
    float acc[4][4];
    #pragma unroll
    for (int i = 0; i < 4; ++i)
        #pragma unroll
        for (int j = 0; j < 4; ++j) acc[i][j] = 0.f;

    for (int kq = 0; kq < 4; ++kq) {
        if (kq) __syncthreads();
        #pragma unroll
        for (int i = 0; i < 4; ++i) {
            int c = t + i * 256;      // 1024 float4 = 32x128 W1 rows
            ((float4*)Ws)[c] = ((const float4*)(W1 + kq * 4096))[c];
        }
        __syncthreads();
        #pragma unroll 2
        for (int k = 0; k < 32; k += 4) {
            float4 av[4], wv[4];
            #pragma unroll
            for (int i = 0; i < 4; ++i)
                av[i] = *(const float4*)(XAs + (4 * rg + i) * 132 + kq * 32 + k);
            #pragma unroll
            for (int dk = 0; dk < 4; ++dk)
                wv[dk] = *(const float4*)(Ws + (k + dk) * 128 + 4 * cg);
            #pragma unroll
            for (int i = 0; i < 4; ++i) {
                acc[i][0] += av[i].x * wv[0].x + av[i].y * wv[1].x + av[i].z * wv[2].x + av[i].w * wv[3].x;
                acc[i][1] += av[i].x * wv[0].y + av[i].y * wv[1].y + av[i].z * wv[2].y + av[i].w * wv[3].y;
                acc[i][2] += av[i].x * wv[0].z + av[i].y * wv[1].z + av[i].z * wv[2].z + av[i].w * wv[3].z;
                acc[i][3] += av[i].x * wv[0].w + av[i].y * wv[1].w + av[i].z * wv[2].w + av[i].w * wv[3].w;
            }
        }
    }
    __syncthreads();                  // all XAs reads done -> reuse as HS

    {
        float4 bb = *(const float4*)(b1 + 4 * cg);
        #pragma unroll
        for (int i = 0; i < 4; ++i) {
            float4 h;
            h.x = fmaxf(acc[i][0] + bb.x, 0.f);
            h.y = fmaxf(acc[i][1] + bb.y, 0.f);
            h.z = fmaxf(acc[i][2] + bb.z, 0.f);
            h.w = fmaxf(acc[i][3] + bb.w, 0.f);
            *(float4*)(XAs + (4 * rg + i) * 132 + 4 * cg) = h;
        }
    }

    // ---- phase 2: [mu|ls] = h @ WB + bias, WB in 2 K-halves ----
    float a3[4][2];
    #pragma unroll
    for (int i = 0; i < 4; ++i) { a3[i][0] = 0.f; a3[i][1] = 0.f; }

    for (int kh = 0; kh < 2; ++kh) {
        __syncthreads();              // HS visible (kh=0) / prior Ws reads done
        #pragma unroll
        for (int i = 0; i < 4; ++i) {
            int c = t + i * 256;      // 1024 float4 = 64 rows x 64 cols
            int row = c >> 4, col4 = (c & 15) << 2;
            int rowg = kh * 64 + row;
            float4 v = (col4 < 32) ? *(const float4*)(Wmu + rowg * 32 + col4)
                                   : *(const float4*)(Wls + rowg * 32 + col4 - 32);
            *(float4*)(Ws + row * 64 + col4) = v;
        }
        __syncthreads();
        #pragma unroll 2
        for (int k = 0; k < 64; k += 4) {
            float4 av[4];
            float2 wv[4];
            #pragma unroll
            for (int i = 0; i < 4; ++i)
                av[i] = *(const float4*)(XAs + (4 * rg + i) * 132 + kh * 64 + k);
            #pragma unroll
            for (int dk = 0; dk < 4; ++dk)
                wv[dk] = *(const float2*)(Ws + (k + dk) * 64 + 2 * cg);
            #pragma unroll
            for (int i = 0; i < 4; ++i) {
                a3[i][0] += av[i].x * wv[0].x + av[i].y * wv[1].x + av[i].z * wv[2].x + av[i].w * wv[3].x;
                a3[i][1] += av[i].x * wv[0].y + av[i].y * wv[1].y + av[i].z * wv[2].y + av[i].w * wv[3].y;
            }
        }
    }
    {
        float2 bv = (cg < 16) ? *(const float2*)(bmu + 2 * cg)
                              : *(const float2*)(bls + 2 * cg - 32);
        #pragma unroll
        for (int i = 0; i < 4; ++i) { a3[i][0] += bv.x; a3[i][1] += bv.y; }
    }

    // exchange mu<->ls with partner lane (cg ^ 16)
    float o3[4][2];
    #pragma unroll
    for (int i = 0; i < 4; ++i) {
        o3[i][0] = __shfl_xor(a3[i][0], 16);
        o3[i][1] = __shfl_xor(a3[i][1], 16);
    }

    // ---- phase 3: z = mu + exp(ls)*eps, KL ----
    float klsum = 0.f;
    if (cg < 16) {                    // this lane holds mu; partner held ls
        int lo = cg;
        #pragma unroll
        for (int i = 0; i < 4; ++i) {
            int rowg = row0 + 4 * rg + i;
            float mu0 = a3[i][0], mu1 = a3[i][1];
            float ls0 = o3[i][0], ls1 = o3[i][1];
            float2 ev = *(const float2*)(eps + (size_t)rowg * 32 + 2 * lo);
            float s0 = expf(ls0), s1 = expf(ls1);
            float2 zv = make_float2(mu0 + s0 * ev.x, mu1 + s1 * ev.y);
            *(float2*)(z + (size_t)rowg * 32 + 2 * lo) = zv;
            klsum += s0 * s0 + mu0 * mu0 - 1.f - 2.f * ls0
                   + s1 * s1 + mu1 * mu1 - 1.f - 2.f * ls1;
        }
    }
    RED[t] = klsum;
    __syncthreads();
    for (int s = 128; s > 0; s >>= 1) {
        if (t < s) RED[t] += RED[t + s];
        __syncthreads();
    }
    if (t == 0) atomicAdd(&kls[g], 0.5f * RED[0]);
}

// ---------------------------------------------------------------------------
// Decoder: 4 blocks per graph (i-quarters), XCD-swizzled like the encoder
// (graph = blockIdx&255) so the graph's z slab stays on one XCD's L2.
__global__ __launch_bounds__(256) void k_decoder(
    const float* __restrict__ z, const unsigned* __restrict__ bitmap,
    float* __restrict__ logp)
{
    __shared__ float zT[32 * 132];
    __shared__ unsigned bm[PW_];
    __shared__ float RED[256];
    int b = blockIdx.x & 255, quar = blockIdx.x >> 8, t = threadIdx.x;

    #pragma unroll
    for (int i = 0; i < 16; ++i) {
        int c = t + i * 256;
        int n = c >> 5, l = c & 31;
        zT[l * 132 + n] = z[((size_t)b * N_ + n) * L_ + l];
    }
    if (t < PW_) bm[t] = bitmap[b * PW_ + t];
    __syncthreads();

    int i0 = quar * 32 + ((t >> 5) << 2);   // 8 i-groups x 4 rows
    int j0 = (t & 31) << 2;                 // 32 j-groups x 4 cols
    float g[4][4];
    #pragma unroll
    for (int a = 0; a < 4; ++a)
        #pragma unroll
        for (int c = 0; c < 4; ++c) g[a][c] = 0.f;

    #pragma unroll 4
    for (int l = 0; l < 32; ++l) {
        float4 a0 = *(const float4*)(zT + l * 132 + i0);
        float4 b0 = *(const float4*)(zT + l * 132 + j0);
        float za[4] = {a0.x, a0.y, a0.z, a0.w};
        float zb[4] = {b0.x, b0.y, b0.z, b0.w};
        #pragma unroll
        for (int a = 0; a < 4; ++a)
            #pragma unroll
            for (int c = 0; c < 4; ++c) g[a][c] += za[a] * zb[c];
    }

    float sum = 0.f;
    #pragma unroll
    for (int a = 0; a < 4; ++a) {
        int i = i0 + a;
        #pragma unroll
        for (int c = 0; c < 4; ++c) {
            int j = j0 + c;
            if (j > i) {
                float lg = g[a][c];
                int p = i * (255 - i) / 2 + (j - i - 1);
                unsigned bit = (bm[p >> 5] >> (p & 31)) & 1u;
                float sp = log1pf(expf(-fabsf(lg))) + fmaxf(lg, 0.f);
                sum += bit ? (lg - sp) : (-sp);
            }
        }
    }
    RED[t] = sum;
    __syncthreads();
    for (int s = 128; s > 0; s >>= 1) {
        if (t < s) RED[t] += RED[t + s];
        __syncthreads();
    }
    if (t == 0) atomicAdd(&logp[b], RED[0]);
}

// ---------------------------------------------------------------------------
__global__ __launch_bounds__(256) void k_finalize(
    const float* __restrict__ kls, const float* __restrict__ logp,
    float* __restrict__ out)
{
    __shared__ float RED[256];
    int t = threadIdx.x;
    RED[t] = logp[t] - kls[t];
    __syncthreads();
    for (int s = 128; s > 0; s >>= 1) {
        if (t < s) RED[t] += RED[t + s];
        __syncthreads();
    }
    if (t == 0) out[0] = -RED[0] * (1.0f / 256.0f);
}

// ---------------------------------------------------------------------------
extern "C" void kernel_launch(void* const* d_in, const int* in_sizes, int n_in,
                              void* d_out, int out_size, void* d_ws, size_t ws_size,
                              hipStream_t stream) {
    const float* x   = (const float*)d_in[0];
    const int*   ei  = (const int*)d_in[1];
    // d_in[2] = batch (unused; block-contiguous layout known)
    const float* eps = (const float*)d_in[3];
    const float* W1  = (const float*)d_in[4];
    const float* b1  = (const float*)d_in[5];
    const float* Wmu = (const float*)d_in[6];
    const float* bmu = (const float*)d_in[7];
    const float* Wls = (const float*)d_in[8];
    const float* bls = (const float*)d_in[9];

    unsigned* wsw = (unsigned*)d_ws;
    unsigned*      ndeg = wsw + NDEG_OFF;
    unsigned*      bm   = wsw + BM_OFF;
    float*         kls  = (float*)(wsw + KLS_OFF);
    float*         logp = (float*)(wsw + LP_OFF);
    unsigned char* adj  = (unsigned char*)(wsw + ADJ_OFF);
    float*         z    = (float*)(wsw + Z_OFF);

    hipMemsetAsync(d_ws, 0, ZERO_WORDS * sizeof(unsigned), stream);

    k_build   <<<E_ / 256, 256, 0, stream>>>(ei, ndeg, adj, bm);
    k_encoder <<<1024, 256, 0, stream>>>(x, ndeg, adj, W1, b1, Wmu, bmu,
                                         Wls, bls, eps, z, kls);
    k_decoder <<<4 * B_, 256, 0, stream>>>(z, bm, logp);
    k_finalize<<<1, 256, 0, stream>>>(kls, logp, (float*)d_out);
}